// Round 10
// baseline (3443.797 us; speedup 1.0000x reference)
//
#include <hip/hip_runtime.h>

#define B64 64
#define SE 512
#define HD 1024
#define ED 512
#define NV 10000
#define TT 20
#define MM 1536
#define MASK_VALF -10000000.0f

// ---- workspace offsets (floats) ----
#define OFF_XA    0          // [inp(512) | h(1024)] x 64, parity A
#define OFF_XB    98304      // parity B
#define OFF_CT    196608     // cT [1024][64]
#define OFF_QF    262144     // qf [64][1024]
#define OFF_FM    327680     // [1024]
#define OFF_FL    328704     // [1024]
#define OFF_FACC  329728     // [1024][1024]
#define OFF_XT2   1378304    // [1536][64]
#define OFF_H1T   1476608    // [1536][64]
#define OFF_ARGV  1574912    // [1250][64]
#define OFF_ARGI  1654912    // [1250][64] (int)
#define OFF_MASKT 1734912    // [10000][64]
#define OFF_BUF   2374912    // [64][20][512]
#define OFF_BUFT  3030272    // [512][20][64]
#define OFF_KVP   3685632    // [64][20][64]
#define OFF_LP    3767552    // [6][10000][64] vocab partials
// end: 7607552 floats ~= 30.4 MB

__device__ __forceinline__ float sigmoidf_(float x) { return 1.f / (1.f + expf(-x)); }

// ---------------- init ----------------
__global__ __launch_bounds__(256) void k_init(const float* __restrict__ h0,
                                              const float* __restrict__ c0,
                                              float* __restrict__ ws) {
  int idx = blockIdx.x * 256 + threadIdx.x, stride = gridDim.x * 256;
  float* xa = ws + OFF_XA;
  float* cT = ws + OFF_CT;
  float* maskT = ws + OFF_MASKT;
  float* buf = ws + OFF_BUF;
  float* bufT = ws + OFF_BUFT;
  for (int i = idx; i < 512 * 64; i += stride) xa[i] = 0.f;  // inp section
  for (int i = idx; i < NV * 64; i += stride) maskT[i] = 0.f;
  for (int i = idx; i < B64 * TT * ED; i += stride) { buf[i] = 0.f; bufT[i] = 0.f; }
  for (int i = idx; i < HD * 64; i += stride) {
    int u = i >> 6, b = i & 63;
    xa[512 * 64 + i] = h0[b * HD + u];  // h section
    cT[i] = c0[b * HD + u];
  }
}

// ---------------- fused LSTM cell: intra-block split-K (4 waves x K/4) + pointwise ----------------
__global__ __launch_bounds__(256) void k_cell(const float* __restrict__ xcur,
                                              const float* __restrict__ w_ih,
                                              const float* __restrict__ w_hh,
                                              const float* __restrict__ b_ih,
                                              const float* __restrict__ b_hh,
                                              float* __restrict__ cT,
                                              float* __restrict__ xnext) {
  __shared__ float wl[8 * 1536];  // 48 KB; reused for cross-wave reduce
  int tid = threadIdx.x;
  int u0 = blockIdx.x * 2;
  for (int i = tid; i < 3072; i += 256) {
    int lr = i / 384, kq = i % 384;
    int k = kq * 4;
    int grow = (lr >> 1) * 1024 + u0 + (lr & 1);
    float4 v;
    if (k < 512) v = *(const float4*)&w_ih[(size_t)grow * 512 + k];
    else v = *(const float4*)&w_hh[(size_t)grow * 1024 + (k - 512)];
    *(float4*)&wl[lr * 1536 + k] = v;
  }
  __syncthreads();
  int lane = tid & 63, wid = tid >> 6;
  int kbase = wid * 384;
  const float* xp = xcur + (size_t)kbase * 64 + lane;
  float acc[8] = {0, 0, 0, 0, 0, 0, 0, 0};
#pragma unroll 2
  for (int k4 = 0; k4 < 96; ++k4) {
    float x0 = xp[(4 * k4 + 0) * 64];
    float x1 = xp[(4 * k4 + 1) * 64];
    float x2 = xp[(4 * k4 + 2) * 64];
    float x3 = xp[(4 * k4 + 3) * 64];
#pragma unroll
    for (int lr = 0; lr < 8; ++lr) {
      const float4 w4 = *(const float4*)&wl[lr * 1536 + kbase + 4 * k4];
      acc[lr] = fmaf(w4.x, x0, acc[lr]);
      acc[lr] = fmaf(w4.y, x1, acc[lr]);
      acc[lr] = fmaf(w4.z, x2, acc[lr]);
      acc[lr] = fmaf(w4.w, x3, acc[lr]);
    }
  }
  __syncthreads();  // weights dead; reuse wl for reduce
#pragma unroll
  for (int lr = 0; lr < 8; ++lr) wl[wid * 512 + lr * 64 + lane] = acc[lr];
  __syncthreads();
  if (tid < 128) {
    int j = tid >> 6, b = tid & 63;
    float g4[4];
#pragma unroll
    for (int g = 0; g < 4; ++g) {
      int lr = g * 2 + j;
      int grow = g * 1024 + u0 + j;
      float v = b_ih[grow] + b_hh[grow];
#pragma unroll
      for (int w = 0; w < 4; ++w) v += wl[w * 512 + lr * 64 + b];  // fixed order: deterministic
      g4[g] = v;
    }
    int u = u0 + j;
    float c = cT[u * 64 + b];
    float cn = sigmoidf_(g4[1]) * c + sigmoidf_(g4[0]) * tanhf(g4[2]);
    float hn = sigmoidf_(g4[3]) * tanhf(cn);
    cT[u * 64 + b] = cn;
    xnext[(512 + u) * 64 + b] = hn;
  }
}

// ---------------- fused q GEMM: intra-block split-K + combine -> qf[b][h] ----------------
__global__ __launch_bounds__(256) void k_q2(const float* __restrict__ h,
                                            const float* __restrict__ w_q,
                                            const float* __restrict__ b_q,
                                            float* __restrict__ qf) {
  __shared__ float wl[8 * 1024];  // 32 KB
  int tid = threadIdx.x;
  int h0 = blockIdx.x * 8;
  for (int i = tid; i < 2048; i += 256) {
    int lr = i >> 8, kq = i & 255;
    *(float4*)&wl[lr * 1024 + kq * 4] = *(const float4*)&w_q[(size_t)(h0 + lr) * 1024 + kq * 4];
  }
  __syncthreads();
  int lane = tid & 63, wid = tid >> 6;
  int kbase = wid * 256;
  const float* xp = h + (size_t)kbase * 64 + lane;
  float acc[8] = {0, 0, 0, 0, 0, 0, 0, 0};
#pragma unroll 2
  for (int k4 = 0; k4 < 64; ++k4) {
    float x0 = xp[(4 * k4 + 0) * 64];
    float x1 = xp[(4 * k4 + 1) * 64];
    float x2 = xp[(4 * k4 + 2) * 64];
    float x3 = xp[(4 * k4 + 3) * 64];
#pragma unroll
    for (int lr = 0; lr < 8; ++lr) {
      const float4 w4 = *(const float4*)&wl[lr * 1024 + kbase + 4 * k4];
      acc[lr] = fmaf(w4.x, x0, acc[lr]);
      acc[lr] = fmaf(w4.y, x1, acc[lr]);
      acc[lr] = fmaf(w4.z, x2, acc[lr]);
      acc[lr] = fmaf(w4.w, x3, acc[lr]);
    }
  }
  __syncthreads();
#pragma unroll
  for (int lr = 0; lr < 8; ++lr) wl[wid * 512 + lr * 64 + lane] = acc[lr];
  __syncthreads();
  for (int e = tid; e < 512; e += 256) {
    int lr = e >> 6, b = e & 63;
    float v = b_q[h0 + lr];
#pragma unroll
    for (int w = 0; w < 4; ++w) v += wl[w * 512 + lr * 64 + b];
    qf[(size_t)b * 1024 + h0 + lr] = v;
  }
}

// ---------------- flash attention: 16 s-splits, 8 rows/wave, pair-pipelined (R4-proven) ----------------
__global__ __launch_bounds__(256) void k_flash(const float* __restrict__ enc,
                                               const int* __restrict__ tlen,
                                               const float* __restrict__ qf,
                                               float* __restrict__ fm, float* __restrict__ fl,
                                               float* __restrict__ facc) {
  __shared__ float lacc[4][1024];
  __shared__ float lml[4][2];
  int b = blockIdx.x >> 4, split = blockIdx.x & 15;
  int tid = threadIdx.x, lane = tid & 63, wid = tid >> 6;
  int len = tlen[b];
  float qv[16];
#pragma unroll
  for (int j = 0; j < 4; ++j) {
    float4 tq = *(const float4*)&qf[(size_t)b * 1024 + j * 256 + lane * 4];
    qv[4 * j + 0] = tq.x; qv[4 * j + 1] = tq.y; qv[4 * j + 2] = tq.z; qv[4 * j + 3] = tq.w;
  }
  const float* base = enc + (size_t)b * SE * HD;
  int s0 = split * 32 + wid * 8;
  int nr = len - s0;
  nr = nr < 0 ? 0 : (nr > 8 ? 8 : nr);
  int npair = nr >> 1;

  float4 cA[4], cB[4], nA[4], nB[4];
  float m = -1e30f, l = 0.f, acc[16];
#pragma unroll
  for (int j = 0; j < 16; ++j) acc[j] = 0.f;

#define LOADROW(d, s)                                                 \
  {                                                                   \
    const float4* rp = (const float4*)(base + (size_t)(s)*HD) + lane; \
    d[0] = rp[0]; d[1] = rp[64]; d[2] = rp[128]; d[3] = rp[192];      \
  }

  if (npair > 0) { LOADROW(cA, s0); LOADROW(cB, s0 + 1); }
  for (int p = 0; p < npair; ++p) {
    if (p + 1 < npair) {
      LOADROW(nA, s0 + 2 * p + 2);
      LOADROW(nB, s0 + 2 * p + 3);
    } else if (nr & 1) {
      LOADROW(nA, s0 + nr - 1);
    }
    float d0 = 0.f, d1 = 0.f;
#pragma unroll
    for (int j = 0; j < 4; ++j) {
      d0 = fmaf(qv[4 * j + 0], cA[j].x, d0); d1 = fmaf(qv[4 * j + 0], cB[j].x, d1);
      d0 = fmaf(qv[4 * j + 1], cA[j].y, d0); d1 = fmaf(qv[4 * j + 1], cB[j].y, d1);
      d0 = fmaf(qv[4 * j + 2], cA[j].z, d0); d1 = fmaf(qv[4 * j + 2], cB[j].z, d1);
      d0 = fmaf(qv[4 * j + 3], cA[j].w, d0); d1 = fmaf(qv[4 * j + 3], cB[j].w, d1);
    }
#pragma unroll
    for (int off = 32; off; off >>= 1) { d0 += __shfl_xor(d0, off, 64); d1 += __shfl_xor(d1, off, 64); }
    d0 = __shfl(d0, 0, 64);
    d1 = __shfl(d1, 0, 64);
    float mn = fmaxf(m, fmaxf(d0, d1));
    float sc = expf(m - mn), p0 = expf(d0 - mn), p1 = expf(d1 - mn);
    l = l * sc + p0 + p1;
#pragma unroll
    for (int j = 0; j < 4; ++j) {
      acc[4 * j + 0] = fmaf(p1, cB[j].x, fmaf(p0, cA[j].x, acc[4 * j + 0] * sc));
      acc[4 * j + 1] = fmaf(p1, cB[j].y, fmaf(p0, cA[j].y, acc[4 * j + 1] * sc));
      acc[4 * j + 2] = fmaf(p1, cB[j].z, fmaf(p0, cA[j].z, acc[4 * j + 2] * sc));
      acc[4 * j + 3] = fmaf(p1, cB[j].w, fmaf(p0, cA[j].w, acc[4 * j + 3] * sc));
    }
    m = mn;
#pragma unroll
    for (int j = 0; j < 4; ++j) { cA[j] = nA[j]; cB[j] = nB[j]; }
  }
  if (nr & 1) {
    if (npair == 0) LOADROW(cA, s0);
    float d0 = 0.f;
#pragma unroll
    for (int j = 0; j < 4; ++j) {
      d0 = fmaf(qv[4 * j + 0], cA[j].x, d0);
      d0 = fmaf(qv[4 * j + 1], cA[j].y, d0);
      d0 = fmaf(qv[4 * j + 2], cA[j].z, d0);
      d0 = fmaf(qv[4 * j + 3], cA[j].w, d0);
    }
#pragma unroll
    for (int off = 32; off; off >>= 1) d0 += __shfl_xor(d0, off, 64);
    d0 = __shfl(d0, 0, 64);
    float mn = fmaxf(m, d0);
    float sc = expf(m - mn), p0 = expf(d0 - mn);
    l = l * sc + p0;
#pragma unroll
    for (int j = 0; j < 4; ++j) {
      acc[4 * j + 0] = fmaf(p0, cA[j].x, acc[4 * j + 0] * sc);
      acc[4 * j + 1] = fmaf(p0, cA[j].y, acc[4 * j + 1] * sc);
      acc[4 * j + 2] = fmaf(p0, cA[j].z, acc[4 * j + 2] * sc);
      acc[4 * j + 3] = fmaf(p0, cA[j].w, acc[4 * j + 3] * sc);
    }
    m = mn;
  }
#undef LOADROW
#pragma unroll
  for (int j = 0; j < 4; ++j)
    *(float4*)&lacc[wid][j * 256 + lane * 4] =
        make_float4(acc[4 * j], acc[4 * j + 1], acc[4 * j + 2], acc[4 * j + 3]);
  if (lane == 0) { lml[wid][0] = m; lml[wid][1] = l; }
  __syncthreads();
  float M = fmaxf(fmaxf(lml[0][0], lml[1][0]), fmaxf(lml[2][0], lml[3][0]));
  float w0 = expf(lml[0][0] - M), w1 = expf(lml[1][0] - M);
  float w2 = expf(lml[2][0] - M), w3 = expf(lml[3][0] - M);
  float L = w0 * lml[0][1] + w1 * lml[1][1] + w2 * lml[2][1] + w3 * lml[3][1];
  int p = b * 16 + split;
  for (int h = tid; h < 1024; h += 256)
    facc[(size_t)p * 1024 + h] =
        w0 * lacc[0][h] + w1 * lacc[1][h] + w2 * lacc[2][h] + w3 * lacc[3][h];
  if (tid == 0) { fm[p] = M; fl[p] = L; }
}

// ---------------- fused: flash combine + history softmax -> xT2 (256 blocks: b x quarter) ----------------
__global__ __launch_bounds__(256) void k_ctx(const float* __restrict__ enc,
                                             const float* __restrict__ fm,
                                             const float* __restrict__ fl,
                                             const float* __restrict__ facc,
                                             const float* __restrict__ kvp,
                                             const float* __restrict__ b_ko,
                                             const float* __restrict__ buf,
                                             const float* __restrict__ inpT,
                                             float* __restrict__ xT2, int tv) {
  __shared__ float pw[TT];
  int b = blockIdx.x >> 2, qd = blockIdx.x & 3;
  int tid = threadIdx.x;
  if (tid < tv) {
    float s = b_ko[0];
    for (int g = 0; g < 64; ++g) s += kvp[((size_t)g * TT + tid) * 64 + b];  // ordered
    pw[tid] = s;
  }
  __syncthreads();
  float mx = -1e30f;
  for (int k = 0; k < tv; ++k) mx = fmaxf(mx, pw[k]);
  float den = 0.f;
  for (int k = 0; k < tv; ++k) den += expf(pw[k] - mx);
  float invd = 1.f / den;
  __syncthreads();
  if (tid < tv) pw[tid] = expf(pw[tid] - mx) * invd;
  __syncthreads();
  float M = -1e30f;
#pragma unroll
  for (int k = 0; k < 16; ++k) M = fmaxf(M, fm[b * 16 + k]);
  float w[16];
  float L = 0.f;
#pragma unroll
  for (int k = 0; k < 16; ++k) {
    w[k] = expf(fm[b * 16 + k] - M);
    L += w[k] * fl[b * 16 + k];
  }
  float inv = 1.f / L;
  {
    int h = qd * 256 + tid;
    float s = 0.f;
#pragma unroll
    for (int k = 0; k < 16; ++k) s += w[k] * facc[(size_t)(b * 16 + k) * 1024 + h];
    xT2[h * 64 + b] = enc[(size_t)b * SE * HD + h] + s * inv;  // sent = enc[:,0,:]
  }
  if (tid < 128) {
    int e = qd * 128 + tid;
    float a = 0.f;
    for (int k = 0; k < tv; ++k) a += pw[k] * buf[((size_t)b * TT + k) * 512 + e];
    xT2[(1024 + e) * 64 + b] = inpT[e * 64 + b] + a;
  }
}

// ---------------- fused h1 GEMM: intra-block split-K + bias+relu -> h1T ----------------
__global__ __launch_bounds__(256) void k_h12(const float* __restrict__ xT2,
                                             const float* __restrict__ w_m1,
                                             const float* __restrict__ b_m1,
                                             float* __restrict__ h1T) {
  __shared__ float wl[8 * 1536];  // 48 KB
  int tid = threadIdx.x;
  int r0 = blockIdx.x * 8;
  for (int i = tid; i < 3072; i += 256) {
    int lr = i / 384, kq = i % 384;
    *(float4*)&wl[lr * 1536 + kq * 4] = *(const float4*)&w_m1[(size_t)(r0 + lr) * MM + kq * 4];
  }
  __syncthreads();
  int lane = tid & 63, wid = tid >> 6;
  int kbase = wid * 384;
  const float* xp = xT2 + (size_t)kbase * 64 + lane;
  float acc[8] = {0, 0, 0, 0, 0, 0, 0, 0};
#pragma unroll 2
  for (int k4 = 0; k4 < 96; ++k4) {
    float x0 = xp[(4 * k4 + 0) * 64];
    float x1 = xp[(4 * k4 + 1) * 64];
    float x2 = xp[(4 * k4 + 2) * 64];
    float x3 = xp[(4 * k4 + 3) * 64];
#pragma unroll
    for (int lr = 0; lr < 8; ++lr) {
      const float4 w4 = *(const float4*)&wl[lr * 1536 + kbase + 4 * k4];
      acc[lr] = fmaf(w4.x, x0, acc[lr]);
      acc[lr] = fmaf(w4.y, x1, acc[lr]);
      acc[lr] = fmaf(w4.z, x2, acc[lr]);
      acc[lr] = fmaf(w4.w, x3, acc[lr]);
    }
  }
  __syncthreads();
#pragma unroll
  for (int lr = 0; lr < 8; ++lr) wl[wid * 512 + lr * 64 + lane] = acc[lr];
  __syncthreads();
  for (int e = tid; e < 512; e += 256) {
    int lr = e >> 6, b = e & 63;
    float v = b_m1[r0 + lr];
#pragma unroll
    for (int w = 0; w < 4; ++w) v += wl[w * 512 + lr * 64 + b];
    h1T[(size_t)(r0 + lr) * 64 + b] = fmaxf(v, 0.f);
  }
}

// ---------------- vocab GEMM: BM=64, split 6, 4x4 thread tiles, reg-prefetched staging ----------------
__global__ __launch_bounds__(256) void k_vocab(const float* __restrict__ h1T,
                                               const float* __restrict__ w_m2,
                                               float* __restrict__ lp) {
  __shared__ float Wl[64 * 36];  // 64 rows x (32 + pad4) = 9 KB
  __shared__ float Xl[32 * 68];  // 32 k x (64 + pad4)   = 8.5 KB
  int tid = threadIdx.x;
  int r0b = blockIdx.x * 64;  // 157 blocks (157*64 = 10048)
  int k0 = blockIdx.y * 256;  // 6 splits
  int tc = tid & 15, tr = tid >> 4;
  int r0 = tr * 4, b0 = tc * 4;
  // staging assignments (2 float4 of W, 2 of X per thread)
  int wf1 = tid + 256;
  int wrow0 = tid >> 3, wkq0 = (tid & 7) * 4;
  int wrow1 = wf1 >> 3, wkq1 = (wf1 & 7) * 4;
  int gr0 = r0b + wrow0; if (gr0 > NV - 1) gr0 = NV - 1;
  int gr1 = r0b + wrow1; if (gr1 > NV - 1) gr1 = NV - 1;
  int xk0 = tid >> 4, xb0 = (tid & 15) * 4;
  int xk1 = wf1 >> 4, xb1 = (wf1 & 15) * 4;

  float4 wp0 = *(const float4*)&w_m2[(size_t)gr0 * MM + k0 + wkq0];
  float4 wp1 = *(const float4*)&w_m2[(size_t)gr1 * MM + k0 + wkq1];
  float4 xp0 = *(const float4*)&h1T[(size_t)(k0 + xk0) * 64 + xb0];
  float4 xp1 = *(const float4*)&h1T[(size_t)(k0 + xk1) * 64 + xb1];
  *(float4*)&Wl[wrow0 * 36 + wkq0] = wp0;
  *(float4*)&Wl[wrow1 * 36 + wkq1] = wp1;
  *(float4*)&Xl[xk0 * 68 + xb0] = xp0;
  *(float4*)&Xl[xk1 * 68 + xb1] = xp1;
  __syncthreads();

  float4 acc[4];
#pragma unroll
  for (int i = 0; i < 4; ++i) acc[i] = make_float4(0.f, 0.f, 0.f, 0.f);

  for (int kt = 0; kt < 8; ++kt) {
    if (kt < 7) {  // issue next tile's loads early; consumed after the sync (latency hidden)
      int kb = k0 + (kt + 1) * 32;
      wp0 = *(const float4*)&w_m2[(size_t)gr0 * MM + kb + wkq0];
      wp1 = *(const float4*)&w_m2[(size_t)gr1 * MM + kb + wkq1];
      xp0 = *(const float4*)&h1T[(size_t)(kb + xk0) * 64 + xb0];
      xp1 = *(const float4*)&h1T[(size_t)(kb + xk1) * 64 + xb1];
    }
#pragma unroll
    for (int kq = 0; kq < 8; ++kq) {
      float4 xv0 = *(const float4*)&Xl[(kq * 4 + 0) * 68 + b0];
      float4 xv1 = *(const float4*)&Xl[(kq * 4 + 1) * 68 + b0];
      float4 xv2 = *(const float4*)&Xl[(kq * 4 + 2) * 68 + b0];
      float4 xv3 = *(const float4*)&Xl[(kq * 4 + 3) * 68 + b0];
#pragma unroll
      for (int i = 0; i < 4; ++i) {
        float4 av = *(const float4*)&Wl[(r0 + i) * 36 + kq * 4];
        acc[i].x = fmaf(av.x, xv0.x, acc[i].x);
        acc[i].y = fmaf(av.x, xv0.y, acc[i].y);
        acc[i].z = fmaf(av.x, xv0.z, acc[i].z);
        acc[i].w = fmaf(av.x, xv0.w, acc[i].w);
        acc[i].x = fmaf(av.y, xv1.x, acc[i].x);
        acc[i].y = fmaf(av.y, xv1.y, acc[i].y);
        acc[i].z = fmaf(av.y, xv1.z, acc[i].z);
        acc[i].w = fmaf(av.y, xv1.w, acc[i].w);
        acc[i].x = fmaf(av.z, xv2.x, acc[i].x);
        acc[i].y = fmaf(av.z, xv2.y, acc[i].y);
        acc[i].z = fmaf(av.z, xv2.z, acc[i].z);
        acc[i].w = fmaf(av.z, xv2.w, acc[i].w);
        acc[i].x = fmaf(av.w, xv3.x, acc[i].x);
        acc[i].y = fmaf(av.w, xv3.y, acc[i].y);
        acc[i].z = fmaf(av.w, xv3.z, acc[i].z);
        acc[i].w = fmaf(av.w, xv3.w, acc[i].w);
      }
    }
    __syncthreads();
    if (kt < 7) {
      *(float4*)&Wl[wrow0 * 36 + wkq0] = wp0;
      *(float4*)&Wl[wrow1 * 36 + wkq1] = wp1;
      *(float4*)&Xl[xk0 * 68 + xb0] = xp0;
      *(float4*)&Xl[xk1 * 68 + xb1] = xp1;
      __syncthreads();
    }
  }
  float* o = lp + (size_t)blockIdx.y * 640000;
#pragma unroll
  for (int i = 0; i < 4; ++i) {
    int r = r0b + r0 + i;
    if (r < NV) *(float4*)&o[(size_t)r * 64 + b0] = acc[i];
  }
}

// ---------------- logits finish: combine 6 + bias + mask + argmax partial + transposed out ----------------
__global__ __launch_bounds__(256) void k_logfin(const float* __restrict__ lp,
                                                const float* __restrict__ b_m2,
                                                const float* __restrict__ maskT,
                                                float* __restrict__ argv, int* __restrict__ argi,
                                                float* __restrict__ out, int t) {
  __shared__ float tile[32][65];
  int lane = threadIdx.x & 63, wid = threadIdx.x >> 6;
  int rg = blockIdx.x * 4 + wid;
  int nb = blockIdx.x * 32;
  if (rg < 1250) {
    int r0 = rg * 8;
    float best = -3.4e38f;
    int bi = 0;
#pragma unroll
    for (int i = 0; i < 8; ++i) {
      int r = r0 + i;
      size_t idx = (size_t)r * 64 + lane;
      float v = b_m2[r] + maskT[idx];
#pragma unroll
      for (int s = 0; s < 6; ++s) v += lp[(size_t)s * 640000 + idx];
      tile[wid * 8 + i][lane] = v;
      if (v > best) { best = v; bi = r; }  // strict >: first-max (np.argmax)
    }
    argv[(size_t)rg * 64 + lane] = best;
    argi[(size_t)rg * 64 + lane] = bi;
  }
  __syncthreads();
  int b = threadIdx.x >> 2, q = threadIdx.x & 3;
  int nloc = q * 8;
  if (nb + nloc < NV) {
    float tmp[8];
#pragma unroll
    for (int c = 0; c < 8; ++c) tmp[c] = tile[nloc + c][b];
    float4* o = (float4*)&out[((size_t)b * TT + t) * NV + nb + nloc];
    o[0] = make_float4(tmp[0], tmp[1], tmp[2], tmp[3]);
    o[1] = make_float4(tmp[4], tmp[5], tmp[6], tmp[7]);
  }
}

// ---------------- final argmax (per-batch block) + feedback ----------------
__global__ __launch_bounds__(256) void k_final(const float* __restrict__ argv,
                                               const int* __restrict__ argi,
                                               const float* __restrict__ emb,
                                               float* __restrict__ maskT,
                                               float* __restrict__ xnext,  // inp section dest
                                               float* __restrict__ buf, float* __restrict__ bufT,
                                               float* __restrict__ out_ids, int t) {
  __shared__ float sv[256];
  __shared__ int si_[256];
  __shared__ int sid;
  int b = blockIdx.x, tid = threadIdx.x;
  float best = -3.4e38f;
  int bi = 0x7fffffff;
  for (int g = tid; g < 1250; g += 256) {
    float v = argv[(size_t)g * 64 + b];
    int idx = argi[(size_t)g * 64 + b];
    if (v > best || (v == best && idx < bi)) { best = v; bi = idx; }
  }
  sv[tid] = best;
  si_[tid] = bi;
  __syncthreads();
  for (int off = 128; off; off >>= 1) {
    if (tid < off) {
      float v2 = sv[tid + off];
      int i2 = si_[tid + off];
      if (v2 > sv[tid] || (v2 == sv[tid] && i2 < si_[tid])) { sv[tid] = v2; si_[tid] = i2; }
    }
    __syncthreads();
  }
  if (tid == 0) {
    sid = si_[0];
    out_ids[b * TT + t] = (float)si_[0];
    if (si_[0] != 1) maskT[(size_t)si_[0] * 64 + b] = MASK_VALF;  // EOS(1) stays 0
  }
  __syncthreads();
  int id = sid;
  for (int e = tid; e < 512; e += 256) {
    float v = emb[(size_t)id * 512 + e];
    xnext[e * 64 + b] = v;  // inp for next step
    buf[((size_t)b * TT + t) * 512 + e] = v;
    bufT[(size_t)e * (TT * 64) + t * 64 + b] = v;
  }
}

// ---------------- incremental history score for buf column j ----------------
__global__ __launch_bounds__(256) void k_kscore(const float* __restrict__ bufT,
                                                const float* __restrict__ w_k,
                                                const float* __restrict__ b_k,
                                                const float* __restrict__ w_ko,
                                                float* __restrict__ kvp, int j) {
  __shared__ float sacc[4][8][64];
  int lane = threadIdx.x & 63, wid = threadIdx.x >> 6;
  int ug = blockIdx.x;  // 0..63
  int u0 = ug * 8;
  int k0 = wid * 128;
  const float* xp = bufT + (size_t)j * 64 + lane;
  float acc[8] = {0, 0, 0, 0, 0, 0, 0, 0};
  for (int k4 = 0; k4 < 32; ++k4) {
    int e = k0 + 4 * k4;
    float x0 = xp[(size_t)(e + 0) * (TT * 64)];
    float x1 = xp[(size_t)(e + 1) * (TT * 64)];
    float x2 = xp[(size_t)(e + 2) * (TT * 64)];
    float x3 = xp[(size_t)(e + 3) * (TT * 64)];
#pragma unroll
    for (int i = 0; i < 8; ++i) {
      const float4 w4 = *(const float4*)&w_k[(size_t)(u0 + i) * 512 + e];
      acc[i] = fmaf(w4.x, x0, acc[i]);
      acc[i] = fmaf(w4.y, x1, acc[i]);
      acc[i] = fmaf(w4.z, x2, acc[i]);
      acc[i] = fmaf(w4.w, x3, acc[i]);
    }
  }
#pragma unroll
  for (int i = 0; i < 8; ++i) sacc[wid][i][lane] = acc[i];
  __syncthreads();
  if (wid == 0) {
    float kp = 0.f;
#pragma unroll
    for (int i = 0; i < 8; ++i) {
      float tot = b_k[u0 + i] + sacc[0][i][lane] + sacc[1][i][lane] + sacc[2][i][lane] +
                  sacc[3][i][lane];
      kp += fmaxf(tot, 0.f) * w_ko[u0 + i];
    }
    kvp[((size_t)ug * TT + j) * 64 + lane] = kp;
  }
}

extern "C" void kernel_launch(void* const* d_in, const int* in_sizes, int n_in,
                              void* d_out, int out_size, void* d_ws, size_t ws_size,
                              hipStream_t stream) {
  const float* enc = (const float*)d_in[0];
  const float* h0 = (const float*)d_in[1];
  const float* c0 = (const float*)d_in[2];
  const int* tlen = (const int*)d_in[3];
  const float* emb = (const float*)d_in[5];
  const float* w_ih = (const float*)d_in[6];
  const float* w_hh = (const float*)d_in[7];
  const float* b_ih = (const float*)d_in[8];
  const float* b_hh = (const float*)d_in[9];
  const float* w_q = (const float*)d_in[10];
  const float* b_q = (const float*)d_in[11];
  const float* w_k = (const float*)d_in[12];
  const float* b_k = (const float*)d_in[13];
  const float* w_ko = (const float*)d_in[14];
  const float* b_ko = (const float*)d_in[15];
  const float* w_m1 = (const float*)d_in[16];
  const float* b_m1 = (const float*)d_in[17];
  const float* w_m2 = (const float*)d_in[18];
  const float* b_m2 = (const float*)d_in[19];

  float* ws = (float*)d_ws;
  float* out_logits = (float*)d_out;
  float* out_ids = out_logits + (size_t)B64 * TT * NV;

  k_init<<<2048, 256, 0, stream>>>(h0, c0, ws);
  k_kscore<<<64, 256, 0, stream>>>(ws + OFF_BUFT, w_k, b_k, w_ko, ws + OFF_KVP, 0);

  for (int t = 0; t < TT; ++t) {
    int tv = (t < 1) ? 1 : t;
    float* xcur = ws + ((t & 1) ? OFF_XB : OFF_XA);
    float* xnext = ws + ((t & 1) ? OFF_XA : OFF_XB);
    k_cell<<<512, 256, 0, stream>>>(xcur, w_ih, w_hh, b_ih, b_hh, ws + OFF_CT, xnext);
    k_q2<<<128, 256, 0, stream>>>(xnext + 512 * 64, w_q, b_q, ws + OFF_QF);
    k_flash<<<1024, 256, 0, stream>>>(enc, tlen, ws + OFF_QF, ws + OFF_FM, ws + OFF_FL,
                                      ws + OFF_FACC);
    k_ctx<<<256, 256, 0, stream>>>(enc, ws + OFF_FM, ws + OFF_FL, ws + OFF_FACC, ws + OFF_KVP,
                                   b_ko, ws + OFF_BUF, xcur, ws + OFF_XT2, tv);
    k_h12<<<192, 256, 0, stream>>>(ws + OFF_XT2, w_m1, b_m1, ws + OFF_H1T);
    k_vocab<<<dim3(157, 6), 256, 0, stream>>>(ws + OFF_H1T, w_m2, ws + OFF_LP);
    k_logfin<<<313, 256, 0, stream>>>(ws + OFF_LP, b_m2, ws + OFF_MASKT, ws + OFF_ARGV,
                                      (int*)(ws + OFF_ARGI), out_logits, t);
    k_final<<<64, 256, 0, stream>>>(ws + OFF_ARGV, (int*)(ws + OFF_ARGI), emb, ws + OFF_MASKT,
                                    xnext, ws + OFF_BUF, ws + OFF_BUFT, out_ids, t);
    if (t < TT - 1)
      k_kscore<<<64, 256, 0, stream>>>(ws + OFF_BUFT, w_k, b_k, w_ko, ws + OFF_KVP, t);
  }
}

// Round 11
// 3406.094 us; speedup vs baseline: 1.0111x; 1.0111x over previous
//
#include <hip/hip_runtime.h>

#define B64 64
#define SE 512
#define HD 1024
#define ED 512
#define NV 10000
#define TT 20
#define MM 1536
#define MASK_VALF -10000000.0f

// ---- workspace offsets (floats) ----
#define OFF_XA    0          // [inp(512) | h(1024)] x 64, parity A
#define OFF_XB    98304      // parity B
#define OFF_CT    196608     // cT [1024][64]
#define OFF_QF    262144     // qf [64][1024]
#define OFF_FM    327680     // [1024]
#define OFF_FL    328704     // [1024]
#define OFF_FACC  329728     // [1024][1024]
#define OFF_XT2   1378304    // [1536][64]
#define OFF_H1T   1476608    // [1536][64]
#define OFF_ARGV  1574912    // [1250][64]
#define OFF_ARGI  1654912    // [1250][64] (int)
#define OFF_MASKT 1734912    // [10000][64]
#define OFF_BUF   2374912    // [64][20][512]
#define OFF_BUFT  3030272    // [512][20][64]
#define OFF_KVP   3685632    // [64][20][64]
#define OFF_LP    3767552    // [6][10000][64] vocab partials
// end: 7607552 floats ~= 30.4 MB

__device__ __forceinline__ float sigmoidf_(float x) { return 1.f / (1.f + expf(-x)); }

// ---------------- init ----------------
__global__ __launch_bounds__(256) void k_init(const float* __restrict__ h0,
                                              const float* __restrict__ c0,
                                              float* __restrict__ ws) {
  int idx = blockIdx.x * 256 + threadIdx.x, stride = gridDim.x * 256;
  float* xa = ws + OFF_XA;
  float* cT = ws + OFF_CT;
  float* maskT = ws + OFF_MASKT;
  float* buf = ws + OFF_BUF;
  float* bufT = ws + OFF_BUFT;
  for (int i = idx; i < 512 * 64; i += stride) xa[i] = 0.f;  // inp section
  for (int i = idx; i < NV * 64; i += stride) maskT[i] = 0.f;
  for (int i = idx; i < B64 * TT * ED; i += stride) { buf[i] = 0.f; bufT[i] = 0.f; }
  for (int i = idx; i < HD * 64; i += stride) {
    int u = i >> 6, b = i & 63;
    xa[512 * 64 + i] = h0[b * HD + u];  // h section
    cT[i] = c0[b * HD + u];
  }
}

// ---------------- fused LSTM cell: intra-block split-K (4 waves x K/4) + pointwise ----------------
__global__ __launch_bounds__(256) void k_cell(const float* __restrict__ xcur,
                                              const float* __restrict__ w_ih,
                                              const float* __restrict__ w_hh,
                                              const float* __restrict__ b_ih,
                                              const float* __restrict__ b_hh,
                                              float* __restrict__ cT,
                                              float* __restrict__ xnext) {
  __shared__ float wl[8 * 1536];  // 48 KB; reused for cross-wave reduce
  int tid = threadIdx.x;
  int u0 = blockIdx.x * 2;
  for (int i = tid; i < 3072; i += 256) {
    int lr = i / 384, kq = i % 384;
    int k = kq * 4;
    int grow = (lr >> 1) * 1024 + u0 + (lr & 1);
    float4 v;
    if (k < 512) v = *(const float4*)&w_ih[(size_t)grow * 512 + k];
    else v = *(const float4*)&w_hh[(size_t)grow * 1024 + (k - 512)];
    *(float4*)&wl[lr * 1536 + k] = v;
  }
  __syncthreads();
  int lane = tid & 63, wid = tid >> 6;
  int kbase = wid * 384;
  const float* xp = xcur + (size_t)kbase * 64 + lane;
  float acc[8] = {0, 0, 0, 0, 0, 0, 0, 0};
#pragma unroll 2
  for (int k4 = 0; k4 < 96; ++k4) {
    float x0 = xp[(4 * k4 + 0) * 64];
    float x1 = xp[(4 * k4 + 1) * 64];
    float x2 = xp[(4 * k4 + 2) * 64];
    float x3 = xp[(4 * k4 + 3) * 64];
#pragma unroll
    for (int lr = 0; lr < 8; ++lr) {
      const float4 w4 = *(const float4*)&wl[lr * 1536 + kbase + 4 * k4];
      acc[lr] = fmaf(w4.x, x0, acc[lr]);
      acc[lr] = fmaf(w4.y, x1, acc[lr]);
      acc[lr] = fmaf(w4.z, x2, acc[lr]);
      acc[lr] = fmaf(w4.w, x3, acc[lr]);
    }
  }
  __syncthreads();  // weights dead; reuse wl for reduce
#pragma unroll
  for (int lr = 0; lr < 8; ++lr) wl[wid * 512 + lr * 64 + lane] = acc[lr];
  __syncthreads();
  if (tid < 128) {
    int j = tid >> 6, b = tid & 63;
    float g4[4];
#pragma unroll
    for (int g = 0; g < 4; ++g) {
      int lr = g * 2 + j;
      int grow = g * 1024 + u0 + j;
      float v = b_ih[grow] + b_hh[grow];
#pragma unroll
      for (int w = 0; w < 4; ++w) v += wl[w * 512 + lr * 64 + b];  // fixed order: deterministic
      g4[g] = v;
    }
    int u = u0 + j;
    float c = cT[u * 64 + b];
    float cn = sigmoidf_(g4[1]) * c + sigmoidf_(g4[0]) * tanhf(g4[2]);
    float hn = sigmoidf_(g4[3]) * tanhf(cn);
    cT[u * 64 + b] = cn;
    xnext[(512 + u) * 64 + b] = hn;
  }
}

// ---------------- fused q GEMM: intra-block split-K + combine -> qf[b][h] ----------------
__global__ __launch_bounds__(256) void k_q2(const float* __restrict__ h,
                                            const float* __restrict__ w_q,
                                            const float* __restrict__ b_q,
                                            float* __restrict__ qf) {
  __shared__ float wl[8 * 1024];  // 32 KB
  int tid = threadIdx.x;
  int h0 = blockIdx.x * 8;
  for (int i = tid; i < 2048; i += 256) {
    int lr = i >> 8, kq = i & 255;
    *(float4*)&wl[lr * 1024 + kq * 4] = *(const float4*)&w_q[(size_t)(h0 + lr) * 1024 + kq * 4];
  }
  __syncthreads();
  int lane = tid & 63, wid = tid >> 6;
  int kbase = wid * 256;
  const float* xp = h + (size_t)kbase * 64 + lane;
  float acc[8] = {0, 0, 0, 0, 0, 0, 0, 0};
#pragma unroll 2
  for (int k4 = 0; k4 < 64; ++k4) {
    float x0 = xp[(4 * k4 + 0) * 64];
    float x1 = xp[(4 * k4 + 1) * 64];
    float x2 = xp[(4 * k4 + 2) * 64];
    float x3 = xp[(4 * k4 + 3) * 64];
#pragma unroll
    for (int lr = 0; lr < 8; ++lr) {
      const float4 w4 = *(const float4*)&wl[lr * 1024 + kbase + 4 * k4];
      acc[lr] = fmaf(w4.x, x0, acc[lr]);
      acc[lr] = fmaf(w4.y, x1, acc[lr]);
      acc[lr] = fmaf(w4.z, x2, acc[lr]);
      acc[lr] = fmaf(w4.w, x3, acc[lr]);
    }
  }
  __syncthreads();
#pragma unroll
  for (int lr = 0; lr < 8; ++lr) wl[wid * 512 + lr * 64 + lane] = acc[lr];
  __syncthreads();
  for (int e = tid; e < 512; e += 256) {
    int lr = e >> 6, b = e & 63;
    float v = b_q[h0 + lr];
#pragma unroll
    for (int w = 0; w < 4; ++w) v += wl[w * 512 + lr * 64 + b];
    qf[(size_t)b * 1024 + h0 + lr] = v;
  }
}

// ---------------- flash attention: 16 s-splits, 8 rows/wave, pair-pipelined (R4-proven) ----------------
__global__ __launch_bounds__(256) void k_flash(const float* __restrict__ enc,
                                               const int* __restrict__ tlen,
                                               const float* __restrict__ qf,
                                               float* __restrict__ fm, float* __restrict__ fl,
                                               float* __restrict__ facc) {
  __shared__ float lacc[4][1024];
  __shared__ float lml[4][2];
  int b = blockIdx.x >> 4, split = blockIdx.x & 15;
  int tid = threadIdx.x, lane = tid & 63, wid = tid >> 6;
  int len = tlen[b];
  float qv[16];
#pragma unroll
  for (int j = 0; j < 4; ++j) {
    float4 tq = *(const float4*)&qf[(size_t)b * 1024 + j * 256 + lane * 4];
    qv[4 * j + 0] = tq.x; qv[4 * j + 1] = tq.y; qv[4 * j + 2] = tq.z; qv[4 * j + 3] = tq.w;
  }
  const float* base = enc + (size_t)b * SE * HD;
  int s0 = split * 32 + wid * 8;
  int nr = len - s0;
  nr = nr < 0 ? 0 : (nr > 8 ? 8 : nr);
  int npair = nr >> 1;

  float4 cA[4], cB[4], nA[4], nB[4];
  float m = -1e30f, l = 0.f, acc[16];
#pragma unroll
  for (int j = 0; j < 16; ++j) acc[j] = 0.f;

#define LOADROW(d, s)                                                 \
  {                                                                   \
    const float4* rp = (const float4*)(base + (size_t)(s)*HD) + lane; \
    d[0] = rp[0]; d[1] = rp[64]; d[2] = rp[128]; d[3] = rp[192];      \
  }

  if (npair > 0) { LOADROW(cA, s0); LOADROW(cB, s0 + 1); }
  for (int p = 0; p < npair; ++p) {
    if (p + 1 < npair) {
      LOADROW(nA, s0 + 2 * p + 2);
      LOADROW(nB, s0 + 2 * p + 3);
    } else if (nr & 1) {
      LOADROW(nA, s0 + nr - 1);
    }
    float d0 = 0.f, d1 = 0.f;
#pragma unroll
    for (int j = 0; j < 4; ++j) {
      d0 = fmaf(qv[4 * j + 0], cA[j].x, d0); d1 = fmaf(qv[4 * j + 0], cB[j].x, d1);
      d0 = fmaf(qv[4 * j + 1], cA[j].y, d0); d1 = fmaf(qv[4 * j + 1], cB[j].y, d1);
      d0 = fmaf(qv[4 * j + 2], cA[j].z, d0); d1 = fmaf(qv[4 * j + 2], cB[j].z, d1);
      d0 = fmaf(qv[4 * j + 3], cA[j].w, d0); d1 = fmaf(qv[4 * j + 3], cB[j].w, d1);
    }
#pragma unroll
    for (int off = 32; off; off >>= 1) { d0 += __shfl_xor(d0, off, 64); d1 += __shfl_xor(d1, off, 64); }
    d0 = __shfl(d0, 0, 64);
    d1 = __shfl(d1, 0, 64);
    float mn = fmaxf(m, fmaxf(d0, d1));
    float sc = expf(m - mn), p0 = expf(d0 - mn), p1 = expf(d1 - mn);
    l = l * sc + p0 + p1;
#pragma unroll
    for (int j = 0; j < 4; ++j) {
      acc[4 * j + 0] = fmaf(p1, cB[j].x, fmaf(p0, cA[j].x, acc[4 * j + 0] * sc));
      acc[4 * j + 1] = fmaf(p1, cB[j].y, fmaf(p0, cA[j].y, acc[4 * j + 1] * sc));
      acc[4 * j + 2] = fmaf(p1, cB[j].z, fmaf(p0, cA[j].z, acc[4 * j + 2] * sc));
      acc[4 * j + 3] = fmaf(p1, cB[j].w, fmaf(p0, cA[j].w, acc[4 * j + 3] * sc));
    }
    m = mn;
#pragma unroll
    for (int j = 0; j < 4; ++j) { cA[j] = nA[j]; cB[j] = nB[j]; }
  }
  if (nr & 1) {
    if (npair == 0) LOADROW(cA, s0);
    float d0 = 0.f;
#pragma unroll
    for (int j = 0; j < 4; ++j) {
      d0 = fmaf(qv[4 * j + 0], cA[j].x, d0);
      d0 = fmaf(qv[4 * j + 1], cA[j].y, d0);
      d0 = fmaf(qv[4 * j + 2], cA[j].z, d0);
      d0 = fmaf(qv[4 * j + 3], cA[j].w, d0);
    }
#pragma unroll
    for (int off = 32; off; off >>= 1) d0 += __shfl_xor(d0, off, 64);
    d0 = __shfl(d0, 0, 64);
    float mn = fmaxf(m, d0);
    float sc = expf(m - mn), p0 = expf(d0 - mn);
    l = l * sc + p0;
#pragma unroll
    for (int j = 0; j < 4; ++j) {
      acc[4 * j + 0] = fmaf(p0, cA[j].x, acc[4 * j + 0] * sc);
      acc[4 * j + 1] = fmaf(p0, cA[j].y, acc[4 * j + 1] * sc);
      acc[4 * j + 2] = fmaf(p0, cA[j].z, acc[4 * j + 2] * sc);
      acc[4 * j + 3] = fmaf(p0, cA[j].w, acc[4 * j + 3] * sc);
    }
    m = mn;
  }
#undef LOADROW
#pragma unroll
  for (int j = 0; j < 4; ++j)
    *(float4*)&lacc[wid][j * 256 + lane * 4] =
        make_float4(acc[4 * j], acc[4 * j + 1], acc[4 * j + 2], acc[4 * j + 3]);
  if (lane == 0) { lml[wid][0] = m; lml[wid][1] = l; }
  __syncthreads();
  float M = fmaxf(fmaxf(lml[0][0], lml[1][0]), fmaxf(lml[2][0], lml[3][0]));
  float w0 = expf(lml[0][0] - M), w1 = expf(lml[1][0] - M);
  float w2 = expf(lml[2][0] - M), w3 = expf(lml[3][0] - M);
  float L = w0 * lml[0][1] + w1 * lml[1][1] + w2 * lml[2][1] + w3 * lml[3][1];
  int p = b * 16 + split;
  for (int h = tid; h < 1024; h += 256)
    facc[(size_t)p * 1024 + h] =
        w0 * lacc[0][h] + w1 * lacc[1][h] + w2 * lacc[2][h] + w3 * lacc[3][h];
  if (tid == 0) { fm[p] = M; fl[p] = L; }
}

// ---------------- fused: flash combine + history softmax -> xT2 (256 blocks: b x quarter) ----------------
__global__ __launch_bounds__(256) void k_ctx(const float* __restrict__ enc,
                                             const float* __restrict__ fm,
                                             const float* __restrict__ fl,
                                             const float* __restrict__ facc,
                                             const float* __restrict__ kvp,
                                             const float* __restrict__ b_ko,
                                             const float* __restrict__ buf,
                                             const float* __restrict__ inpT,
                                             float* __restrict__ xT2, int tv) {
  __shared__ float pw[TT];
  int b = blockIdx.x >> 2, qd = blockIdx.x & 3;
  int tid = threadIdx.x;
  if (tid < tv) {
    float s = b_ko[0];
    for (int g = 0; g < 64; ++g) s += kvp[((size_t)g * TT + tid) * 64 + b];  // ordered
    pw[tid] = s;
  }
  __syncthreads();
  float mx = -1e30f;
  for (int k = 0; k < tv; ++k) mx = fmaxf(mx, pw[k]);
  float den = 0.f;
  for (int k = 0; k < tv; ++k) den += expf(pw[k] - mx);
  float invd = 1.f / den;
  __syncthreads();
  if (tid < tv) pw[tid] = expf(pw[tid] - mx) * invd;
  __syncthreads();
  float M = -1e30f;
#pragma unroll
  for (int k = 0; k < 16; ++k) M = fmaxf(M, fm[b * 16 + k]);
  float w[16];
  float L = 0.f;
#pragma unroll
  for (int k = 0; k < 16; ++k) {
    w[k] = expf(fm[b * 16 + k] - M);
    L += w[k] * fl[b * 16 + k];
  }
  float inv = 1.f / L;
  {
    int h = qd * 256 + tid;
    float s = 0.f;
#pragma unroll
    for (int k = 0; k < 16; ++k) s += w[k] * facc[(size_t)(b * 16 + k) * 1024 + h];
    xT2[h * 64 + b] = enc[(size_t)b * SE * HD + h] + s * inv;  // sent = enc[:,0,:]
  }
  if (tid < 128) {
    int e = qd * 128 + tid;
    float a = 0.f;
    for (int k = 0; k < tv; ++k) a += pw[k] * buf[((size_t)b * TT + k) * 512 + e];
    xT2[(1024 + e) * 64 + b] = inpT[e * 64 + b] + a;
  }
}

// ---------------- fused h1 GEMM: intra-block split-K + bias+relu -> h1T ----------------
__global__ __launch_bounds__(256) void k_h12(const float* __restrict__ xT2,
                                             const float* __restrict__ w_m1,
                                             const float* __restrict__ b_m1,
                                             float* __restrict__ h1T) {
  __shared__ float wl[8 * 1536];  // 48 KB
  int tid = threadIdx.x;
  int r0 = blockIdx.x * 8;
  for (int i = tid; i < 3072; i += 256) {
    int lr = i / 384, kq = i % 384;
    *(float4*)&wl[lr * 1536 + kq * 4] = *(const float4*)&w_m1[(size_t)(r0 + lr) * MM + kq * 4];
  }
  __syncthreads();
  int lane = tid & 63, wid = tid >> 6;
  int kbase = wid * 384;
  const float* xp = xT2 + (size_t)kbase * 64 + lane;
  float acc[8] = {0, 0, 0, 0, 0, 0, 0, 0};
#pragma unroll 2
  for (int k4 = 0; k4 < 96; ++k4) {
    float x0 = xp[(4 * k4 + 0) * 64];
    float x1 = xp[(4 * k4 + 1) * 64];
    float x2 = xp[(4 * k4 + 2) * 64];
    float x3 = xp[(4 * k4 + 3) * 64];
#pragma unroll
    for (int lr = 0; lr < 8; ++lr) {
      const float4 w4 = *(const float4*)&wl[lr * 1536 + kbase + 4 * k4];
      acc[lr] = fmaf(w4.x, x0, acc[lr]);
      acc[lr] = fmaf(w4.y, x1, acc[lr]);
      acc[lr] = fmaf(w4.z, x2, acc[lr]);
      acc[lr] = fmaf(w4.w, x3, acc[lr]);
    }
  }
  __syncthreads();
#pragma unroll
  for (int lr = 0; lr < 8; ++lr) wl[wid * 512 + lr * 64 + lane] = acc[lr];
  __syncthreads();
  for (int e = tid; e < 512; e += 256) {
    int lr = e >> 6, b = e & 63;
    float v = b_m1[r0 + lr];
#pragma unroll
    for (int w = 0; w < 4; ++w) v += wl[w * 512 + lr * 64 + b];
    h1T[(size_t)(r0 + lr) * 64 + b] = fmaxf(v, 0.f);
  }
}

// ---------------- vocab GEMM: BM=128, split 6, 8x4 thread tiles, DOUBLE-BUFFERED LDS ----------------
__global__ __launch_bounds__(256) void k_vocab(const float* __restrict__ h1T,
                                               const float* __restrict__ w_m2,
                                               float* __restrict__ lp) {
  __shared__ float Wl[2][128 * 36];  // 2 x 18 KB
  __shared__ float Xl[2][32 * 68];   // 2 x 8.5 KB
  int tid = threadIdx.x;
  int r0b = blockIdx.x * 128;  // 79 blocks
  int k0 = blockIdx.y * 256;   // 6 splits
  int tc = tid & 15, tr = tid >> 4;
  int r0 = tr * 8, b0 = tc * 4;
  // staging assignments: 4 W float4 + 2 X float4 per thread
  int wrow[4], wkq[4], gr[4], xk[2], xb[2];
#pragma unroll
  for (int j = 0; j < 4; ++j) {
    int f = tid + 256 * j;
    wrow[j] = f >> 3;
    wkq[j] = (f & 7) * 4;
    int g = r0b + wrow[j];
    gr[j] = g > NV - 1 ? NV - 1 : g;
  }
#pragma unroll
  for (int j = 0; j < 2; ++j) {
    int f = tid + 256 * j;
    xk[j] = f >> 4;
    xb[j] = (f & 15) * 4;
  }
  // stage tile 0 into buffer 0
#pragma unroll
  for (int j = 0; j < 4; ++j)
    *(float4*)&Wl[0][wrow[j] * 36 + wkq[j]] = *(const float4*)&w_m2[(size_t)gr[j] * MM + k0 + wkq[j]];
#pragma unroll
  for (int j = 0; j < 2; ++j)
    *(float4*)&Xl[0][xk[j] * 68 + xb[j]] = *(const float4*)&h1T[(size_t)(k0 + xk[j]) * 64 + xb[j]];
  __syncthreads();

  float4 acc[8];
#pragma unroll
  for (int i = 0; i < 8; ++i) acc[i] = make_float4(0.f, 0.f, 0.f, 0.f);
  float4 wp[4], xp[2];

  for (int kt = 0; kt < 8; ++kt) {
    int cur = kt & 1;
    if (kt < 7) {  // issue next tile's global loads; latency hides under compute below
      int kb = k0 + (kt + 1) * 32;
#pragma unroll
      for (int j = 0; j < 4; ++j) wp[j] = *(const float4*)&w_m2[(size_t)gr[j] * MM + kb + wkq[j]];
#pragma unroll
      for (int j = 0; j < 2; ++j) xp[j] = *(const float4*)&h1T[(size_t)(kb + xk[j]) * 64 + xb[j]];
    }
    const float* Wc = Wl[cur];
    const float* Xc = Xl[cur];
#pragma unroll 2
    for (int kq = 0; kq < 8; ++kq) {
      float4 xv0 = *(const float4*)&Xc[(kq * 4 + 0) * 68 + b0];
      float4 xv1 = *(const float4*)&Xc[(kq * 4 + 1) * 68 + b0];
      float4 xv2 = *(const float4*)&Xc[(kq * 4 + 2) * 68 + b0];
      float4 xv3 = *(const float4*)&Xc[(kq * 4 + 3) * 68 + b0];
#pragma unroll
      for (int i = 0; i < 8; ++i) {
        float4 av = *(const float4*)&Wc[(r0 + i) * 36 + kq * 4];
        acc[i].x = fmaf(av.x, xv0.x, acc[i].x);
        acc[i].y = fmaf(av.x, xv0.y, acc[i].y);
        acc[i].z = fmaf(av.x, xv0.z, acc[i].z);
        acc[i].w = fmaf(av.x, xv0.w, acc[i].w);
        acc[i].x = fmaf(av.y, xv1.x, acc[i].x);
        acc[i].y = fmaf(av.y, xv1.y, acc[i].y);
        acc[i].z = fmaf(av.y, xv1.z, acc[i].z);
        acc[i].w = fmaf(av.y, xv1.w, acc[i].w);
        acc[i].x = fmaf(av.z, xv2.x, acc[i].x);
        acc[i].y = fmaf(av.z, xv2.y, acc[i].y);
        acc[i].z = fmaf(av.z, xv2.z, acc[i].z);
        acc[i].w = fmaf(av.z, xv2.w, acc[i].w);
        acc[i].x = fmaf(av.w, xv3.x, acc[i].x);
        acc[i].y = fmaf(av.w, xv3.y, acc[i].y);
        acc[i].z = fmaf(av.w, xv3.z, acc[i].z);
        acc[i].w = fmaf(av.w, xv3.w, acc[i].w);
      }
    }
    if (kt < 7) {  // write next tile into the other buffer; ONE sync per tile
      int nxt = cur ^ 1;
#pragma unroll
      for (int j = 0; j < 4; ++j) *(float4*)&Wl[nxt][wrow[j] * 36 + wkq[j]] = wp[j];
#pragma unroll
      for (int j = 0; j < 2; ++j) *(float4*)&Xl[nxt][xk[j] * 68 + xb[j]] = xp[j];
      __syncthreads();
    }
  }
  float* o = lp + (size_t)blockIdx.y * 640000;
#pragma unroll
  for (int i = 0; i < 8; ++i) {
    int r = r0b + r0 + i;
    if (r < NV) *(float4*)&o[(size_t)r * 64 + b0] = acc[i];
  }
}

// ---------------- logits finish: combine 6 + bias + mask + argmax partial + transposed out ----------------
__global__ __launch_bounds__(256) void k_logfin(const float* __restrict__ lp,
                                                const float* __restrict__ b_m2,
                                                const float* __restrict__ maskT,
                                                float* __restrict__ argv, int* __restrict__ argi,
                                                float* __restrict__ out, int t) {
  __shared__ float tile[32][65];
  int lane = threadIdx.x & 63, wid = threadIdx.x >> 6;
  int rg = blockIdx.x * 4 + wid;
  int nb = blockIdx.x * 32;
  if (rg < 1250) {
    int r0 = rg * 8;
    float best = -3.4e38f;
    int bi = 0;
#pragma unroll
    for (int i = 0; i < 8; ++i) {
      int r = r0 + i;
      size_t idx = (size_t)r * 64 + lane;
      float v = b_m2[r] + maskT[idx];
#pragma unroll
      for (int s = 0; s < 6; ++s) v += lp[(size_t)s * 640000 + idx];
      tile[wid * 8 + i][lane] = v;
      if (v > best) { best = v; bi = r; }  // strict >: first-max (np.argmax)
    }
    argv[(size_t)rg * 64 + lane] = best;
    argi[(size_t)rg * 64 + lane] = bi;
  }
  __syncthreads();
  int b = threadIdx.x >> 2, q = threadIdx.x & 3;
  int nloc = q * 8;
  if (nb + nloc < NV) {
    float tmp[8];
#pragma unroll
    for (int c = 0; c < 8; ++c) tmp[c] = tile[nloc + c][b];
    float4* o = (float4*)&out[((size_t)b * TT + t) * NV + nb + nloc];
    o[0] = make_float4(tmp[0], tmp[1], tmp[2], tmp[3]);
    o[1] = make_float4(tmp[4], tmp[5], tmp[6], tmp[7]);
  }
}

// ---------------- final argmax (per-batch block) + feedback ----------------
__global__ __launch_bounds__(256) void k_final(const float* __restrict__ argv,
                                               const int* __restrict__ argi,
                                               const float* __restrict__ emb,
                                               float* __restrict__ maskT,
                                               float* __restrict__ xnext,  // inp section dest
                                               float* __restrict__ buf, float* __restrict__ bufT,
                                               float* __restrict__ out_ids, int t) {
  __shared__ float sv[256];
  __shared__ int si_[256];
  __shared__ int sid;
  int b = blockIdx.x, tid = threadIdx.x;
  float best = -3.4e38f;
  int bi = 0x7fffffff;
  for (int g = tid; g < 1250; g += 256) {
    float v = argv[(size_t)g * 64 + b];
    int idx = argi[(size_t)g * 64 + b];
    if (v > best || (v == best && idx < bi)) { best = v; bi = idx; }
  }
  sv[tid] = best;
  si_[tid] = bi;
  __syncthreads();
  for (int off = 128; off; off >>= 1) {
    if (tid < off) {
      float v2 = sv[tid + off];
      int i2 = si_[tid + off];
      if (v2 > sv[tid] || (v2 == sv[tid] && i2 < si_[tid])) { sv[tid] = v2; si_[tid] = i2; }
    }
    __syncthreads();
  }
  if (tid == 0) {
    sid = si_[0];
    out_ids[b * TT + t] = (float)si_[0];
    if (si_[0] != 1) maskT[(size_t)si_[0] * 64 + b] = MASK_VALF;  // EOS(1) stays 0
  }
  __syncthreads();
  int id = sid;
  for (int e = tid; e < 512; e += 256) {
    float v = emb[(size_t)id * 512 + e];
    xnext[e * 64 + b] = v;  // inp for next step
    buf[((size_t)b * TT + t) * 512 + e] = v;
    bufT[(size_t)e * (TT * 64) + t * 64 + b] = v;
  }
}

// ---------------- incremental history score for buf column j ----------------
__global__ __launch_bounds__(256) void k_kscore(const float* __restrict__ bufT,
                                                const float* __restrict__ w_k,
                                                const float* __restrict__ b_k,
                                                const float* __restrict__ w_ko,
                                                float* __restrict__ kvp, int j) {
  __shared__ float sacc[4][8][64];
  int lane = threadIdx.x & 63, wid = threadIdx.x >> 6;
  int ug = blockIdx.x;  // 0..63
  int u0 = ug * 8;
  int k0 = wid * 128;
  const float* xp = bufT + (size_t)j * 64 + lane;
  float acc[8] = {0, 0, 0, 0, 0, 0, 0, 0};
  for (int k4 = 0; k4 < 32; ++k4) {
    int e = k0 + 4 * k4;
    float x0 = xp[(size_t)(e + 0) * (TT * 64)];
    float x1 = xp[(size_t)(e + 1) * (TT * 64)];
    float x2 = xp[(size_t)(e + 2) * (TT * 64)];
    float x3 = xp[(size_t)(e + 3) * (TT * 64)];
#pragma unroll
    for (int i = 0; i < 8; ++i) {
      const float4 w4 = *(const float4*)&w_k[(size_t)(u0 + i) * 512 + e];
      acc[i] = fmaf(w4.x, x0, acc[i]);
      acc[i] = fmaf(w4.y, x1, acc[i]);
      acc[i] = fmaf(w4.z, x2, acc[i]);
      acc[i] = fmaf(w4.w, x3, acc[i]);
    }
  }
#pragma unroll
  for (int i = 0; i < 8; ++i) sacc[wid][i][lane] = acc[i];
  __syncthreads();
  if (wid == 0) {
    float kp = 0.f;
#pragma unroll
    for (int i = 0; i < 8; ++i) {
      float tot = b_k[u0 + i] + sacc[0][i][lane] + sacc[1][i][lane] + sacc[2][i][lane] +
                  sacc[3][i][lane];
      kp += fmaxf(tot, 0.f) * w_ko[u0 + i];
    }
    kvp[((size_t)ug * TT + j) * 64 + lane] = kp;
  }
}

extern "C" void kernel_launch(void* const* d_in, const int* in_sizes, int n_in,
                              void* d_out, int out_size, void* d_ws, size_t ws_size,
                              hipStream_t stream) {
  const float* enc = (const float*)d_in[0];
  const float* h0 = (const float*)d_in[1];
  const float* c0 = (const float*)d_in[2];
  const int* tlen = (const int*)d_in[3];
  const float* emb = (const float*)d_in[5];
  const float* w_ih = (const float*)d_in[6];
  const float* w_hh = (const float*)d_in[7];
  const float* b_ih = (const float*)d_in[8];
  const float* b_hh = (const float*)d_in[9];
  const float* w_q = (const float*)d_in[10];
  const float* b_q = (const float*)d_in[11];
  const float* w_k = (const float*)d_in[12];
  const float* b_k = (const float*)d_in[13];
  const float* w_ko = (const float*)d_in[14];
  const float* b_ko = (const float*)d_in[15];
  const float* w_m1 = (const float*)d_in[16];
  const float* b_m1 = (const float*)d_in[17];
  const float* w_m2 = (const float*)d_in[18];
  const float* b_m2 = (const float*)d_in[19];

  float* ws = (float*)d_ws;
  float* out_logits = (float*)d_out;
  float* out_ids = out_logits + (size_t)B64 * TT * NV;

  k_init<<<2048, 256, 0, stream>>>(h0, c0, ws);
  k_kscore<<<64, 256, 0, stream>>>(ws + OFF_BUFT, w_k, b_k, w_ko, ws + OFF_KVP, 0);

  for (int t = 0; t < TT; ++t) {
    int tv = (t < 1) ? 1 : t;
    float* xcur = ws + ((t & 1) ? OFF_XB : OFF_XA);
    float* xnext = ws + ((t & 1) ? OFF_XA : OFF_XB);
    k_cell<<<512, 256, 0, stream>>>(xcur, w_ih, w_hh, b_ih, b_hh, ws + OFF_CT, xnext);
    k_q2<<<128, 256, 0, stream>>>(xnext + 512 * 64, w_q, b_q, ws + OFF_QF);
    k_flash<<<1024, 256, 0, stream>>>(enc, tlen, ws + OFF_QF, ws + OFF_FM, ws + OFF_FL,
                                      ws + OFF_FACC);
    k_ctx<<<256, 256, 0, stream>>>(enc, ws + OFF_FM, ws + OFF_FL, ws + OFF_FACC, ws + OFF_KVP,
                                   b_ko, ws + OFF_BUF, xcur, ws + OFF_XT2, tv);
    k_h12<<<192, 256, 0, stream>>>(ws + OFF_XT2, w_m1, b_m1, ws + OFF_H1T);
    k_vocab<<<dim3(79, 6), 256, 0, stream>>>(ws + OFF_H1T, w_m2, ws + OFF_LP);
    k_logfin<<<313, 256, 0, stream>>>(ws + OFF_LP, b_m2, ws + OFF_MASKT, ws + OFF_ARGV,
                                      (int*)(ws + OFF_ARGI), out_logits, t);
    k_final<<<64, 256, 0, stream>>>(ws + OFF_ARGV, (int*)(ws + OFF_ARGI), emb, ws + OFF_MASKT,
                                    xnext, ws + OFF_BUF, ws + OFF_BUFT, out_ids, t);
    if (t < TT - 1)
      k_kscore<<<64, 256, 0, stream>>>(ws + OFF_BUFT, w_k, b_k, w_ko, ws + OFF_KVP, t);
  }
}

// Round 12
// 2963.860 us; speedup vs baseline: 1.1619x; 1.1492x over previous
//
#include <hip/hip_runtime.h>

#define B64 64
#define SE 512
#define HD 1024
#define ED 512
#define NV 10000
#define TT 20
#define MM 1536
#define MASK_VALF -10000000.0f

// ---- workspace offsets (floats) ----
#define OFF_XA    0          // [inp(512) | h(1024)] x 64, parity A
#define OFF_XB    98304      // parity B
#define OFF_CT    196608     // cT [1024][64]
#define OFF_QF    262144     // qf [64][1024]
#define OFF_FM    327680     // [1024]
#define OFF_FL    328704     // [1024]
#define OFF_FACC  329728     // [1024][1024]
#define OFF_XT2   1378304    // [1536][64]
#define OFF_H1T   1476608    // [1536][64]
#define OFF_ARGV  1574912    // [1250][64]
#define OFF_ARGI  1654912    // [1250][64] (int)
#define OFF_MASKT 1734912    // [10000][64]
#define OFF_BUF   2374912    // [64][20][512]
#define OFF_BUFT  3030272    // [512][20][64]
#define OFF_KVP   3685632    // [64][20][64]
#define OFF_LP    3767552    // [6][10000][64] vocab partials
// end: 7607552 floats ~= 30.4 MB

__device__ __forceinline__ float sigmoidf_(float x) { return 1.f / (1.f + expf(-x)); }

// ---------------- init ----------------
__global__ __launch_bounds__(256) void k_init(const float* __restrict__ h0,
                                              const float* __restrict__ c0,
                                              float* __restrict__ ws) {
  int idx = blockIdx.x * 256 + threadIdx.x, stride = gridDim.x * 256;
  float* xa = ws + OFF_XA;
  float* cT = ws + OFF_CT;
  float* maskT = ws + OFF_MASKT;
  float* buf = ws + OFF_BUF;
  float* bufT = ws + OFF_BUFT;
  for (int i = idx; i < 512 * 64; i += stride) xa[i] = 0.f;  // inp section
  for (int i = idx; i < NV * 64; i += stride) maskT[i] = 0.f;
  for (int i = idx; i < B64 * TT * ED; i += stride) { buf[i] = 0.f; bufT[i] = 0.f; }
  for (int i = idx; i < HD * 64; i += stride) {
    int u = i >> 6, b = i & 63;
    xa[512 * 64 + i] = h0[b * HD + u];  // h section
    cT[i] = c0[b * HD + u];
  }
}

// ---------------- fused: LSTM cell (blocks 0-511) + history kscore column j (blocks 512-575) ----------------
// Both halves depend only on k_final(t-1) outputs, so they share one dispatch.
__global__ __launch_bounds__(256) void k_cellks(const float* __restrict__ xcur,
                                                const float* __restrict__ w_ih,
                                                const float* __restrict__ w_hh,
                                                const float* __restrict__ b_ih,
                                                const float* __restrict__ b_hh,
                                                float* __restrict__ cT,
                                                float* __restrict__ xnext,
                                                const float* __restrict__ bufT,
                                                const float* __restrict__ w_k,
                                                const float* __restrict__ b_k,
                                                const float* __restrict__ w_ko,
                                                float* __restrict__ kvp, int j) {
  __shared__ float wl[8 * 1536];  // 48 KB; cell staging / kscore reduce / cross-wave reduce
  int tid = threadIdx.x, lane = tid & 63, wid = tid >> 6;

  if (blockIdx.x >= 512) {
    // ---- kscore half: score contribution for buf column j, unit group ug ----
    int ug = blockIdx.x - 512;  // 0..63
    int u0 = ug * 8;
    int k0 = wid * 128;
    const float* xp = bufT + (size_t)j * 64 + lane;
    float acc[8] = {0, 0, 0, 0, 0, 0, 0, 0};
    for (int k4 = 0; k4 < 32; ++k4) {
      int e = k0 + 4 * k4;
      float x0 = xp[(size_t)(e + 0) * (TT * 64)];
      float x1 = xp[(size_t)(e + 1) * (TT * 64)];
      float x2 = xp[(size_t)(e + 2) * (TT * 64)];
      float x3 = xp[(size_t)(e + 3) * (TT * 64)];
#pragma unroll
      for (int i = 0; i < 8; ++i) {
        const float4 w4 = *(const float4*)&w_k[(size_t)(u0 + i) * 512 + e];
        acc[i] = fmaf(w4.x, x0, acc[i]);
        acc[i] = fmaf(w4.y, x1, acc[i]);
        acc[i] = fmaf(w4.z, x2, acc[i]);
        acc[i] = fmaf(w4.w, x3, acc[i]);
      }
    }
    float* sacc = wl;  // [4][8][64]
#pragma unroll
    for (int i = 0; i < 8; ++i) sacc[(wid * 8 + i) * 64 + lane] = acc[i];
    __syncthreads();
    if (wid == 0) {
      float kp = 0.f;
#pragma unroll
      for (int i = 0; i < 8; ++i) {
        float tot = b_k[u0 + i] + sacc[(0 * 8 + i) * 64 + lane] + sacc[(1 * 8 + i) * 64 + lane] +
                    sacc[(2 * 8 + i) * 64 + lane] + sacc[(3 * 8 + i) * 64 + lane];
        kp += fmaxf(tot, 0.f) * w_ko[u0 + i];
      }
      kvp[((size_t)ug * TT + j) * 64 + lane] = kp;
    }
    return;
  }

  // ---- cell half: intra-block split-K (4 waves x K/4) + pointwise ----
  int u0 = blockIdx.x * 2;
  for (int i = tid; i < 3072; i += 256) {
    int lr = i / 384, kq = i % 384;
    int k = kq * 4;
    int grow = (lr >> 1) * 1024 + u0 + (lr & 1);
    float4 v;
    if (k < 512) v = *(const float4*)&w_ih[(size_t)grow * 512 + k];
    else v = *(const float4*)&w_hh[(size_t)grow * 1024 + (k - 512)];
    *(float4*)&wl[lr * 1536 + k] = v;
  }
  __syncthreads();
  int kbase = wid * 384;
  const float* xp = xcur + (size_t)kbase * 64 + lane;
  float acc[8] = {0, 0, 0, 0, 0, 0, 0, 0};
#pragma unroll 2
  for (int k4 = 0; k4 < 96; ++k4) {
    float x0 = xp[(4 * k4 + 0) * 64];
    float x1 = xp[(4 * k4 + 1) * 64];
    float x2 = xp[(4 * k4 + 2) * 64];
    float x3 = xp[(4 * k4 + 3) * 64];
#pragma unroll
    for (int lr = 0; lr < 8; ++lr) {
      const float4 w4 = *(const float4*)&wl[lr * 1536 + kbase + 4 * k4];
      acc[lr] = fmaf(w4.x, x0, acc[lr]);
      acc[lr] = fmaf(w4.y, x1, acc[lr]);
      acc[lr] = fmaf(w4.z, x2, acc[lr]);
      acc[lr] = fmaf(w4.w, x3, acc[lr]);
    }
  }
  __syncthreads();  // weights dead; reuse wl for reduce
#pragma unroll
  for (int lr = 0; lr < 8; ++lr) wl[wid * 512 + lr * 64 + lane] = acc[lr];
  __syncthreads();
  if (tid < 128) {
    int jj = tid >> 6, b = tid & 63;
    float g4[4];
#pragma unroll
    for (int g = 0; g < 4; ++g) {
      int lr = g * 2 + jj;
      int grow = g * 1024 + u0 + jj;
      float v = b_ih[grow] + b_hh[grow];
#pragma unroll
      for (int w = 0; w < 4; ++w) v += wl[w * 512 + lr * 64 + b];  // fixed order: deterministic
      g4[g] = v;
    }
    int u = u0 + jj;
    float c = cT[u * 64 + b];
    float cn = sigmoidf_(g4[1]) * c + sigmoidf_(g4[0]) * tanhf(g4[2]);
    float hn = sigmoidf_(g4[3]) * tanhf(cn);
    cT[u * 64 + b] = cn;
    xnext[(512 + u) * 64 + b] = hn;
  }
}

// ---------------- fused q GEMM: intra-block split-K + combine -> qf[b][h] ----------------
__global__ __launch_bounds__(256) void k_q2(const float* __restrict__ h,
                                            const float* __restrict__ w_q,
                                            const float* __restrict__ b_q,
                                            float* __restrict__ qf) {
  __shared__ float wl[8 * 1024];  // 32 KB
  int tid = threadIdx.x;
  int h0 = blockIdx.x * 8;
  for (int i = tid; i < 2048; i += 256) {
    int lr = i >> 8, kq = i & 255;
    *(float4*)&wl[lr * 1024 + kq * 4] = *(const float4*)&w_q[(size_t)(h0 + lr) * 1024 + kq * 4];
  }
  __syncthreads();
  int lane = tid & 63, wid = tid >> 6;
  int kbase = wid * 256;
  const float* xp = h + (size_t)kbase * 64 + lane;
  float acc[8] = {0, 0, 0, 0, 0, 0, 0, 0};
#pragma unroll 2
  for (int k4 = 0; k4 < 64; ++k4) {
    float x0 = xp[(4 * k4 + 0) * 64];
    float x1 = xp[(4 * k4 + 1) * 64];
    float x2 = xp[(4 * k4 + 2) * 64];
    float x3 = xp[(4 * k4 + 3) * 64];
#pragma unroll
    for (int lr = 0; lr < 8; ++lr) {
      const float4 w4 = *(const float4*)&wl[lr * 1024 + kbase + 4 * k4];
      acc[lr] = fmaf(w4.x, x0, acc[lr]);
      acc[lr] = fmaf(w4.y, x1, acc[lr]);
      acc[lr] = fmaf(w4.z, x2, acc[lr]);
      acc[lr] = fmaf(w4.w, x3, acc[lr]);
    }
  }
  __syncthreads();
#pragma unroll
  for (int lr = 0; lr < 8; ++lr) wl[wid * 512 + lr * 64 + lane] = acc[lr];
  __syncthreads();
  for (int e = tid; e < 512; e += 256) {
    int lr = e >> 6, b = e & 63;
    float v = b_q[h0 + lr];
#pragma unroll
    for (int w = 0; w < 4; ++w) v += wl[w * 512 + lr * 64 + b];
    qf[(size_t)b * 1024 + h0 + lr] = v;
  }
}

// ---------------- flash attention: 16 s-splits, 8 rows/wave, pair-pipelined (R4-proven) ----------------
__global__ __launch_bounds__(256) void k_flash(const float* __restrict__ enc,
                                               const int* __restrict__ tlen,
                                               const float* __restrict__ qf,
                                               float* __restrict__ fm, float* __restrict__ fl,
                                               float* __restrict__ facc) {
  __shared__ float lacc[4][1024];
  __shared__ float lml[4][2];
  int b = blockIdx.x >> 4, split = blockIdx.x & 15;
  int tid = threadIdx.x, lane = tid & 63, wid = tid >> 6;
  int len = tlen[b];
  float qv[16];
#pragma unroll
  for (int j = 0; j < 4; ++j) {
    float4 tq = *(const float4*)&qf[(size_t)b * 1024 + j * 256 + lane * 4];
    qv[4 * j + 0] = tq.x; qv[4 * j + 1] = tq.y; qv[4 * j + 2] = tq.z; qv[4 * j + 3] = tq.w;
  }
  const float* base = enc + (size_t)b * SE * HD;
  int s0 = split * 32 + wid * 8;
  int nr = len - s0;
  nr = nr < 0 ? 0 : (nr > 8 ? 8 : nr);
  int npair = nr >> 1;

  float4 cA[4], cB[4], nA[4], nB[4];
  float m = -1e30f, l = 0.f, acc[16];
#pragma unroll
  for (int j = 0; j < 16; ++j) acc[j] = 0.f;

#define LOADROW(d, s)                                                 \
  {                                                                   \
    const float4* rp = (const float4*)(base + (size_t)(s)*HD) + lane; \
    d[0] = rp[0]; d[1] = rp[64]; d[2] = rp[128]; d[3] = rp[192];      \
  }

  if (npair > 0) { LOADROW(cA, s0); LOADROW(cB, s0 + 1); }
  for (int p = 0; p < npair; ++p) {
    if (p + 1 < npair) {
      LOADROW(nA, s0 + 2 * p + 2);
      LOADROW(nB, s0 + 2 * p + 3);
    } else if (nr & 1) {
      LOADROW(nA, s0 + nr - 1);
    }
    float d0 = 0.f, d1 = 0.f;
#pragma unroll
    for (int j = 0; j < 4; ++j) {
      d0 = fmaf(qv[4 * j + 0], cA[j].x, d0); d1 = fmaf(qv[4 * j + 0], cB[j].x, d1);
      d0 = fmaf(qv[4 * j + 1], cA[j].y, d0); d1 = fmaf(qv[4 * j + 1], cB[j].y, d1);
      d0 = fmaf(qv[4 * j + 2], cA[j].z, d0); d1 = fmaf(qv[4 * j + 2], cB[j].z, d1);
      d0 = fmaf(qv[4 * j + 3], cA[j].w, d0); d1 = fmaf(qv[4 * j + 3], cB[j].w, d1);
    }
#pragma unroll
    for (int off = 32; off; off >>= 1) { d0 += __shfl_xor(d0, off, 64); d1 += __shfl_xor(d1, off, 64); }
    d0 = __shfl(d0, 0, 64);
    d1 = __shfl(d1, 0, 64);
    float mn = fmaxf(m, fmaxf(d0, d1));
    float sc = expf(m - mn), p0 = expf(d0 - mn), p1 = expf(d1 - mn);
    l = l * sc + p0 + p1;
#pragma unroll
    for (int j = 0; j < 4; ++j) {
      acc[4 * j + 0] = fmaf(p1, cB[j].x, fmaf(p0, cA[j].x, acc[4 * j + 0] * sc));
      acc[4 * j + 1] = fmaf(p1, cB[j].y, fmaf(p0, cA[j].y, acc[4 * j + 1] * sc));
      acc[4 * j + 2] = fmaf(p1, cB[j].z, fmaf(p0, cA[j].z, acc[4 * j + 2] * sc));
      acc[4 * j + 3] = fmaf(p1, cB[j].w, fmaf(p0, cA[j].w, acc[4 * j + 3] * sc));
    }
    m = mn;
#pragma unroll
    for (int j = 0; j < 4; ++j) { cA[j] = nA[j]; cB[j] = nB[j]; }
  }
  if (nr & 1) {
    if (npair == 0) LOADROW(cA, s0);
    float d0 = 0.f;
#pragma unroll
    for (int j = 0; j < 4; ++j) {
      d0 = fmaf(qv[4 * j + 0], cA[j].x, d0);
      d0 = fmaf(qv[4 * j + 1], cA[j].y, d0);
      d0 = fmaf(qv[4 * j + 2], cA[j].z, d0);
      d0 = fmaf(qv[4 * j + 3], cA[j].w, d0);
    }
#pragma unroll
    for (int off = 32; off; off >>= 1) d0 += __shfl_xor(d0, off, 64);
    d0 = __shfl(d0, 0, 64);
    float mn = fmaxf(m, d0);
    float sc = expf(m - mn), p0 = expf(d0 - mn);
    l = l * sc + p0;
#pragma unroll
    for (int j = 0; j < 4; ++j) {
      acc[4 * j + 0] = fmaf(p0, cA[j].x, acc[4 * j + 0] * sc);
      acc[4 * j + 1] = fmaf(p0, cA[j].y, acc[4 * j + 1] * sc);
      acc[4 * j + 2] = fmaf(p0, cA[j].z, acc[4 * j + 2] * sc);
      acc[4 * j + 3] = fmaf(p0, cA[j].w, acc[4 * j + 3] * sc);
    }
    m = mn;
  }
#undef LOADROW
#pragma unroll
  for (int j = 0; j < 4; ++j)
    *(float4*)&lacc[wid][j * 256 + lane * 4] =
        make_float4(acc[4 * j], acc[4 * j + 1], acc[4 * j + 2], acc[4 * j + 3]);
  if (lane == 0) { lml[wid][0] = m; lml[wid][1] = l; }
  __syncthreads();
  float M = fmaxf(fmaxf(lml[0][0], lml[1][0]), fmaxf(lml[2][0], lml[3][0]));
  float w0 = expf(lml[0][0] - M), w1 = expf(lml[1][0] - M);
  float w2 = expf(lml[2][0] - M), w3 = expf(lml[3][0] - M);
  float L = w0 * lml[0][1] + w1 * lml[1][1] + w2 * lml[2][1] + w3 * lml[3][1];
  int p = b * 16 + split;
  for (int h = tid; h < 1024; h += 256)
    facc[(size_t)p * 1024 + h] =
        w0 * lacc[0][h] + w1 * lacc[1][h] + w2 * lacc[2][h] + w3 * lacc[3][h];
  if (tid == 0) { fm[p] = M; fl[p] = L; }
}

// ---------------- fused: flash combine + history softmax -> xT2 (256 blocks: b x quarter) ----------------
__global__ __launch_bounds__(256) void k_ctx(const float* __restrict__ enc,
                                             const float* __restrict__ fm,
                                             const float* __restrict__ fl,
                                             const float* __restrict__ facc,
                                             const float* __restrict__ kvp,
                                             const float* __restrict__ b_ko,
                                             const float* __restrict__ buf,
                                             const float* __restrict__ inpT,
                                             float* __restrict__ xT2, int tv) {
  __shared__ float pw[TT];
  int b = blockIdx.x >> 2, qd = blockIdx.x & 3;
  int tid = threadIdx.x;
  if (tid < tv) {
    float s = b_ko[0];
    for (int g = 0; g < 64; ++g) s += kvp[((size_t)g * TT + tid) * 64 + b];  // ordered
    pw[tid] = s;
  }
  __syncthreads();
  float mx = -1e30f;
  for (int k = 0; k < tv; ++k) mx = fmaxf(mx, pw[k]);
  float den = 0.f;
  for (int k = 0; k < tv; ++k) den += expf(pw[k] - mx);
  float invd = 1.f / den;
  __syncthreads();
  if (tid < tv) pw[tid] = expf(pw[tid] - mx) * invd;
  __syncthreads();
  float M = -1e30f;
#pragma unroll
  for (int k = 0; k < 16; ++k) M = fmaxf(M, fm[b * 16 + k]);
  float w[16];
  float L = 0.f;
#pragma unroll
  for (int k = 0; k < 16; ++k) {
    w[k] = expf(fm[b * 16 + k] - M);
    L += w[k] * fl[b * 16 + k];
  }
  float inv = 1.f / L;
  {
    int h = qd * 256 + tid;
    float s = 0.f;
#pragma unroll
    for (int k = 0; k < 16; ++k) s += w[k] * facc[(size_t)(b * 16 + k) * 1024 + h];
    xT2[h * 64 + b] = enc[(size_t)b * SE * HD + h] + s * inv;  // sent = enc[:,0,:]
  }
  if (tid < 128) {
    int e = qd * 128 + tid;
    float a = 0.f;
    for (int k = 0; k < tv; ++k) a += pw[k] * buf[((size_t)b * TT + k) * 512 + e];
    xT2[(1024 + e) * 64 + b] = inpT[e * 64 + b] + a;
  }
}

// ---------------- fused h1 GEMM: intra-block split-K + bias+relu -> h1T ----------------
__global__ __launch_bounds__(256) void k_h12(const float* __restrict__ xT2,
                                             const float* __restrict__ w_m1,
                                             const float* __restrict__ b_m1,
                                             float* __restrict__ h1T) {
  __shared__ float wl[8 * 1536];  // 48 KB
  int tid = threadIdx.x;
  int r0 = blockIdx.x * 8;
  for (int i = tid; i < 3072; i += 256) {
    int lr = i / 384, kq = i % 384;
    *(float4*)&wl[lr * 1536 + kq * 4] = *(const float4*)&w_m1[(size_t)(r0 + lr) * MM + kq * 4];
  }
  __syncthreads();
  int lane = tid & 63, wid = tid >> 6;
  int kbase = wid * 384;
  const float* xp = xT2 + (size_t)kbase * 64 + lane;
  float acc[8] = {0, 0, 0, 0, 0, 0, 0, 0};
#pragma unroll 2
  for (int k4 = 0; k4 < 96; ++k4) {
    float x0 = xp[(4 * k4 + 0) * 64];
    float x1 = xp[(4 * k4 + 1) * 64];
    float x2 = xp[(4 * k4 + 2) * 64];
    float x3 = xp[(4 * k4 + 3) * 64];
#pragma unroll
    for (int lr = 0; lr < 8; ++lr) {
      const float4 w4 = *(const float4*)&wl[lr * 1536 + kbase + 4 * k4];
      acc[lr] = fmaf(w4.x, x0, acc[lr]);
      acc[lr] = fmaf(w4.y, x1, acc[lr]);
      acc[lr] = fmaf(w4.z, x2, acc[lr]);
      acc[lr] = fmaf(w4.w, x3, acc[lr]);
    }
  }
  __syncthreads();
#pragma unroll
  for (int lr = 0; lr < 8; ++lr) wl[wid * 512 + lr * 64 + lane] = acc[lr];
  __syncthreads();
  for (int e = tid; e < 512; e += 256) {
    int lr = e >> 6, b = e & 63;
    float v = b_m1[r0 + lr];
#pragma unroll
    for (int w = 0; w < 4; ++w) v += wl[w * 512 + lr * 64 + b];
    h1T[(size_t)(r0 + lr) * 64 + b] = fmaxf(v, 0.f);
  }
}

// ---------------- vocab GEMM: BM=128, split 6, 8x4 thread tiles (R9-proven geometry) ----------------
__global__ __launch_bounds__(256) void k_vocab(const float* __restrict__ h1T,
                                               const float* __restrict__ w_m2,
                                               float* __restrict__ lp) {
  __shared__ float Wl[128 * 36];  // [row][36] (BK=32 + pad 4) -> 18 KB
  __shared__ float Xl[32 * 68];   // [k][68]  (64 + pad 4)     -> 8.5 KB
  int tid = threadIdx.x;
  int r0b = blockIdx.x * 128;  // 0..78
  int k0 = blockIdx.y * 256;   // 0..5
  int tc = tid & 15, tr = tid >> 4;
  int r0 = tr * 8, b0 = tc * 4;
  float4 acc[8];
#pragma unroll
  for (int i = 0; i < 8; ++i) acc[i] = make_float4(0.f, 0.f, 0.f, 0.f);
  for (int kt = 0; kt < 8; ++kt) {
    int kbase = k0 + kt * 32;
    // stage W tile: 128 rows x 32 k (1024 float4)
#pragma unroll
    for (int j = 0; j < 4; ++j) {
      int f = tid + 256 * j;
      int row = f >> 3, kkq = (f & 7) * 4;
      int gr = r0b + row;
      if (gr > NV - 1) gr = NV - 1;
      *(float4*)&Wl[row * 36 + kkq] = *(const float4*)&w_m2[(size_t)gr * MM + kbase + kkq];
    }
    // stage X tile: 32 k x 64 b (512 float4)
#pragma unroll
    for (int j = 0; j < 2; ++j) {
      int f = tid + 256 * j;
      int kk = f >> 4, bq = (f & 15) * 4;
      *(float4*)&Xl[kk * 68 + bq] = *(const float4*)&h1T[(size_t)(kbase + kk) * 64 + bq];
    }
    __syncthreads();
#pragma unroll 2
    for (int kq = 0; kq < 8; ++kq) {
      float4 xv0 = *(const float4*)&Xl[(kq * 4 + 0) * 68 + b0];
      float4 xv1 = *(const float4*)&Xl[(kq * 4 + 1) * 68 + b0];
      float4 xv2 = *(const float4*)&Xl[(kq * 4 + 2) * 68 + b0];
      float4 xv3 = *(const float4*)&Xl[(kq * 4 + 3) * 68 + b0];
#pragma unroll
      for (int i = 0; i < 8; ++i) {
        float4 av = *(const float4*)&Wl[(r0 + i) * 36 + kq * 4];
        acc[i].x = fmaf(av.x, xv0.x, acc[i].x);
        acc[i].y = fmaf(av.x, xv0.y, acc[i].y);
        acc[i].z = fmaf(av.x, xv0.z, acc[i].z);
        acc[i].w = fmaf(av.x, xv0.w, acc[i].w);
        acc[i].x = fmaf(av.y, xv1.x, acc[i].x);
        acc[i].y = fmaf(av.y, xv1.y, acc[i].y);
        acc[i].z = fmaf(av.y, xv1.z, acc[i].z);
        acc[i].w = fmaf(av.y, xv1.w, acc[i].w);
        acc[i].x = fmaf(av.z, xv2.x, acc[i].x);
        acc[i].y = fmaf(av.z, xv2.y, acc[i].y);
        acc[i].z = fmaf(av.z, xv2.z, acc[i].z);
        acc[i].w = fmaf(av.z, xv2.w, acc[i].w);
        acc[i].x = fmaf(av.w, xv3.x, acc[i].x);
        acc[i].y = fmaf(av.w, xv3.y, acc[i].y);
        acc[i].z = fmaf(av.w, xv3.z, acc[i].z);
        acc[i].w = fmaf(av.w, xv3.w, acc[i].w);
      }
    }
    __syncthreads();
  }
  float* o = lp + (size_t)blockIdx.y * 640000;
#pragma unroll
  for (int i = 0; i < 8; ++i) {
    int r = r0b + r0 + i;
    if (r < NV) *(float4*)&o[(size_t)r * 64 + b0] = acc[i];
  }
}

// ---------------- logits finish: combine 6 + bias + mask + argmax partial + transposed out ----------------
__global__ __launch_bounds__(256) void k_logfin(const float* __restrict__ lp,
                                                const float* __restrict__ b_m2,
                                                const float* __restrict__ maskT,
                                                float* __restrict__ argv, int* __restrict__ argi,
                                                float* __restrict__ out, int t) {
  __shared__ float tile[32][65];
  int lane = threadIdx.x & 63, wid = threadIdx.x >> 6;
  int rg = blockIdx.x * 4 + wid;
  int nb = blockIdx.x * 32;
  if (rg < 1250) {
    int r0 = rg * 8;
    float best = -3.4e38f;
    int bi = 0;
#pragma unroll
    for (int i = 0; i < 8; ++i) {
      int r = r0 + i;
      size_t idx = (size_t)r * 64 + lane;
      float v = b_m2[r] + maskT[idx];
#pragma unroll
      for (int s = 0; s < 6; ++s) v += lp[(size_t)s * 640000 + idx];
      tile[wid * 8 + i][lane] = v;
      if (v > best) { best = v; bi = r; }  // strict >: first-max (np.argmax)
    }
    argv[(size_t)rg * 64 + lane] = best;
    argi[(size_t)rg * 64 + lane] = bi;
  }
  __syncthreads();
  int b = threadIdx.x >> 2, q = threadIdx.x & 3;
  int nloc = q * 8;
  if (nb + nloc < NV) {
    float tmp[8];
#pragma unroll
    for (int c = 0; c < 8; ++c) tmp[c] = tile[nloc + c][b];
    float4* o = (float4*)&out[((size_t)b * TT + t) * NV + nb + nloc];
    o[0] = make_float4(tmp[0], tmp[1], tmp[2], tmp[3]);
    o[1] = make_float4(tmp[4], tmp[5], tmp[6], tmp[7]);
  }
}

// ---------------- final argmax (per-batch block) + feedback ----------------
__global__ __launch_bounds__(256) void k_final(const float* __restrict__ argv,
                                               const int* __restrict__ argi,
                                               const float* __restrict__ emb,
                                               float* __restrict__ maskT,
                                               float* __restrict__ xnext,  // inp section dest
                                               float* __restrict__ buf, float* __restrict__ bufT,
                                               float* __restrict__ out_ids, int t) {
  __shared__ float sv[256];
  __shared__ int si_[256];
  __shared__ int sid;
  int b = blockIdx.x, tid = threadIdx.x;
  float best = -3.4e38f;
  int bi = 0x7fffffff;
  for (int g = tid; g < 1250; g += 256) {
    float v = argv[(size_t)g * 64 + b];
    int idx = argi[(size_t)g * 64 + b];
    if (v > best || (v == best && idx < bi)) { best = v; bi = idx; }
  }
  sv[tid] = best;
  si_[tid] = bi;
  __syncthreads();
  for (int off = 128; off; off >>= 1) {
    if (tid < off) {
      float v2 = sv[tid + off];
      int i2 = si_[tid + off];
      if (v2 > sv[tid] || (v2 == sv[tid] && i2 < si_[tid])) { sv[tid] = v2; si_[tid] = i2; }
    }
    __syncthreads();
  }
  if (tid == 0) {
    sid = si_[0];
    out_ids[b * TT + t] = (float)si_[0];
    if (si_[0] != 1) maskT[(size_t)si_[0] * 64 + b] = MASK_VALF;  // EOS(1) stays 0
  }
  __syncthreads();
  int id = sid;
  for (int e = tid; e < 512; e += 256) {
    float v = emb[(size_t)id * 512 + e];
    xnext[e * 64 + b] = v;  // inp for next step
    buf[((size_t)b * TT + t) * 512 + e] = v;
    bufT[(size_t)e * (TT * 64) + t * 64 + b] = v;
  }
}

extern "C" void kernel_launch(void* const* d_in, const int* in_sizes, int n_in,
                              void* d_out, int out_size, void* d_ws, size_t ws_size,
                              hipStream_t stream) {
  const float* enc = (const float*)d_in[0];
  const float* h0 = (const float*)d_in[1];
  const float* c0 = (const float*)d_in[2];
  const int* tlen = (const int*)d_in[3];
  const float* emb = (const float*)d_in[5];
  const float* w_ih = (const float*)d_in[6];
  const float* w_hh = (const float*)d_in[7];
  const float* b_ih = (const float*)d_in[8];
  const float* b_hh = (const float*)d_in[9];
  const float* w_q = (const float*)d_in[10];
  const float* b_q = (const float*)d_in[11];
  const float* w_k = (const float*)d_in[12];
  const float* b_k = (const float*)d_in[13];
  const float* w_ko = (const float*)d_in[14];
  const float* b_ko = (const float*)d_in[15];
  const float* w_m1 = (const float*)d_in[16];
  const float* b_m1 = (const float*)d_in[17];
  const float* w_m2 = (const float*)d_in[18];
  const float* b_m2 = (const float*)d_in[19];

  float* ws = (float*)d_ws;
  float* out_logits = (float*)d_out;
  float* out_ids = out_logits + (size_t)B64 * TT * NV;

  k_init<<<2048, 256, 0, stream>>>(h0, c0, ws);

  for (int t = 0; t < TT; ++t) {
    int tv = (t < 1) ? 1 : t;
    int jcol = (t == 0) ? 0 : t - 1;  // kscore column: zeros at t=0, else buf col written at t-1
    float* xcur = ws + ((t & 1) ? OFF_XB : OFF_XA);
    float* xnext = ws + ((t & 1) ? OFF_XA : OFF_XB);
    k_cellks<<<576, 256, 0, stream>>>(xcur, w_ih, w_hh, b_ih, b_hh, ws + OFF_CT, xnext,
                                      ws + OFF_BUFT, w_k, b_k, w_ko, ws + OFF_KVP, jcol);
    k_q2<<<128, 256, 0, stream>>>(xnext + 512 * 64, w_q, b_q, ws + OFF_QF);
    k_flash<<<1024, 256, 0, stream>>>(enc, tlen, ws + OFF_QF, ws + OFF_FM, ws + OFF_FL,
                                      ws + OFF_FACC);
    k_ctx<<<256, 256, 0, stream>>>(enc, ws + OFF_FM, ws + OFF_FL, ws + OFF_FACC, ws + OFF_KVP,
                                   b_ko, ws + OFF_BUF, xcur, ws + OFF_XT2, tv);
    k_h12<<<192, 256, 0, stream>>>(ws + OFF_XT2, w_m1, b_m1, ws + OFF_H1T);
    k_vocab<<<dim3(79, 6), 256, 0, stream>>>(ws + OFF_H1T, w_m2, ws + OFF_LP);
    k_logfin<<<313, 256, 0, stream>>>(ws + OFF_LP, b_m2, ws + OFF_MASKT, ws + OFF_ARGV,
                                      (int*)(ws + OFF_ARGI), out_logits, t);
    k_final<<<64, 256, 0, stream>>>(ws + OFF_ARGV, (int*)(ws + OFF_ARGI), emb, ws + OFF_MASKT,
                                    xnext, ws + OFF_BUF, ws + OFF_BUFT, out_ids, t);
  }
}

// Round 13
// 2764.904 us; speedup vs baseline: 1.2455x; 1.0720x over previous
//
#include <hip/hip_runtime.h>

#define B64 64
#define SE 512
#define HD 1024
#define ED 512
#define NV 10000
#define TT 20
#define MM 1536
#define MASK_VALF -10000000.0f

// ---- workspace offsets (floats) ----
#define OFF_XA    0          // [inp(512) | h(1024)] x 64, parity A
#define OFF_XB    98304      // parity B
#define OFF_CT    196608     // cT [1024][64]
#define OFF_QF    262144     // qf [64][1024]
#define OFF_FM    327680     // [1024]
#define OFF_FL    328704     // [1024]
#define OFF_FACC  329728     // [1024][1024]
#define OFF_XT2   1378304    // [1536][64]
#define OFF_H1T   1476608    // [1536][64]
#define OFF_ARGV  1574912    // [1250][64]
#define OFF_ARGI  1654912    // [1250][64] (int)
#define OFF_MASKT 1734912    // [10000][64]
#define OFF_BUF   2374912    // [64][20][512]
#define OFF_BUFT  3030272    // [512][20][64]
#define OFF_KVP   3685632    // [64][20][64]
#define OFF_LP    3767552    // [6][10000][64] vocab partials
// end: 7607552 floats ~= 30.4 MB

__device__ __forceinline__ float sigmoidf_(float x) { return 1.f / (1.f + expf(-x)); }

// ---------------- init ----------------
__global__ __launch_bounds__(256) void k_init(const float* __restrict__ h0,
                                              const float* __restrict__ c0,
                                              float* __restrict__ ws) {
  int idx = blockIdx.x * 256 + threadIdx.x, stride = gridDim.x * 256;
  float* xa = ws + OFF_XA;
  float* cT = ws + OFF_CT;
  float* maskT = ws + OFF_MASKT;
  float* buf = ws + OFF_BUF;
  float* bufT = ws + OFF_BUFT;
  for (int i = idx; i < 512 * 64; i += stride) xa[i] = 0.f;  // inp section
  for (int i = idx; i < NV * 64; i += stride) maskT[i] = 0.f;
  for (int i = idx; i < B64 * TT * ED; i += stride) { buf[i] = 0.f; bufT[i] = 0.f; }
  for (int i = idx; i < HD * 64; i += stride) {
    int u = i >> 6, b = i & 63;
    xa[512 * 64 + i] = h0[b * HD + u];  // h section
    cT[i] = c0[b * HD + u];
  }
}

// ---------------- fused: LSTM cell (blocks 0-511) + history kscore column j (blocks 512-575) ----------------
__global__ __launch_bounds__(256) void k_cellks(const float* __restrict__ xcur,
                                                const float* __restrict__ w_ih,
                                                const float* __restrict__ w_hh,
                                                const float* __restrict__ b_ih,
                                                const float* __restrict__ b_hh,
                                                float* __restrict__ cT,
                                                float* __restrict__ xnext,
                                                const float* __restrict__ bufT,
                                                const float* __restrict__ w_k,
                                                const float* __restrict__ b_k,
                                                const float* __restrict__ w_ko,
                                                float* __restrict__ kvp, int j) {
  __shared__ float wl[8 * 1536];  // 48 KB; cell staging / kscore reduce / cross-wave reduce
  int tid = threadIdx.x, lane = tid & 63, wid = tid >> 6;

  if (blockIdx.x >= 512) {
    // ---- kscore half: score contribution for buf column j, unit group ug ----
    int ug = blockIdx.x - 512;  // 0..63
    int u0 = ug * 8;
    int k0 = wid * 128;
    const float* xp = bufT + (size_t)j * 64 + lane;
    float acc[8] = {0, 0, 0, 0, 0, 0, 0, 0};
    for (int k4 = 0; k4 < 32; ++k4) {
      int e = k0 + 4 * k4;
      float x0 = xp[(size_t)(e + 0) * (TT * 64)];
      float x1 = xp[(size_t)(e + 1) * (TT * 64)];
      float x2 = xp[(size_t)(e + 2) * (TT * 64)];
      float x3 = xp[(size_t)(e + 3) * (TT * 64)];
#pragma unroll
      for (int i = 0; i < 8; ++i) {
        const float4 w4 = *(const float4*)&w_k[(size_t)(u0 + i) * 512 + e];
        acc[i] = fmaf(w4.x, x0, acc[i]);
        acc[i] = fmaf(w4.y, x1, acc[i]);
        acc[i] = fmaf(w4.z, x2, acc[i]);
        acc[i] = fmaf(w4.w, x3, acc[i]);
      }
    }
    float* sacc = wl;  // [4][8][64]
#pragma unroll
    for (int i = 0; i < 8; ++i) sacc[(wid * 8 + i) * 64 + lane] = acc[i];
    __syncthreads();
    if (wid == 0) {
      float kp = 0.f;
#pragma unroll
      for (int i = 0; i < 8; ++i) {
        float tot = b_k[u0 + i] + sacc[(0 * 8 + i) * 64 + lane] + sacc[(1 * 8 + i) * 64 + lane] +
                    sacc[(2 * 8 + i) * 64 + lane] + sacc[(3 * 8 + i) * 64 + lane];
        kp += fmaxf(tot, 0.f) * w_ko[u0 + i];
      }
      kvp[((size_t)ug * TT + j) * 64 + lane] = kp;
    }
    return;
  }

  // ---- cell half: intra-block split-K (4 waves x K/4) + pointwise ----
  int u0 = blockIdx.x * 2;
  for (int i = tid; i < 3072; i += 256) {
    int lr = i / 384, kq = i % 384;
    int k = kq * 4;
    int grow = (lr >> 1) * 1024 + u0 + (lr & 1);
    float4 v;
    if (k < 512) v = *(const float4*)&w_ih[(size_t)grow * 512 + k];
    else v = *(const float4*)&w_hh[(size_t)grow * 1024 + (k - 512)];
    *(float4*)&wl[lr * 1536 + k] = v;
  }
  __syncthreads();
  int kbase = wid * 384;
  const float* xp = xcur + (size_t)kbase * 64 + lane;
  float acc[8] = {0, 0, 0, 0, 0, 0, 0, 0};
#pragma unroll 2
  for (int k4 = 0; k4 < 96; ++k4) {
    float x0 = xp[(4 * k4 + 0) * 64];
    float x1 = xp[(4 * k4 + 1) * 64];
    float x2 = xp[(4 * k4 + 2) * 64];
    float x3 = xp[(4 * k4 + 3) * 64];
#pragma unroll
    for (int lr = 0; lr < 8; ++lr) {
      const float4 w4 = *(const float4*)&wl[lr * 1536 + kbase + 4 * k4];
      acc[lr] = fmaf(w4.x, x0, acc[lr]);
      acc[lr] = fmaf(w4.y, x1, acc[lr]);
      acc[lr] = fmaf(w4.z, x2, acc[lr]);
      acc[lr] = fmaf(w4.w, x3, acc[lr]);
    }
  }
  __syncthreads();  // weights dead; reuse wl for reduce
#pragma unroll
  for (int lr = 0; lr < 8; ++lr) wl[wid * 512 + lr * 64 + lane] = acc[lr];
  __syncthreads();
  if (tid < 128) {
    int jj = tid >> 6, b = tid & 63;
    float g4[4];
#pragma unroll
    for (int g = 0; g < 4; ++g) {
      int lr = g * 2 + jj;
      int grow = g * 1024 + u0 + jj;
      float v = b_ih[grow] + b_hh[grow];
#pragma unroll
      for (int w = 0; w < 4; ++w) v += wl[w * 512 + lr * 64 + b];  // fixed order: deterministic
      g4[g] = v;
    }
    int u = u0 + jj;
    float c = cT[u * 64 + b];
    float cn = sigmoidf_(g4[1]) * c + sigmoidf_(g4[0]) * tanhf(g4[2]);
    float hn = sigmoidf_(g4[3]) * tanhf(cn);
    cT[u * 64 + b] = cn;
    xnext[(512 + u) * 64 + b] = hn;
  }
}

// ---------------- fused: q GEMM (blocks 0-127) + history-attn finish (blocks 128-191) ----------------
// Both halves depend only on k_cellks/k_final(t-1) outputs — share one dispatch.
// hist half writes xT2[1024:1536) = inp + attn_last (identical math/order to old k_ctx).
__global__ __launch_bounds__(256) void k_q2h(const float* __restrict__ h,
                                             const float* __restrict__ w_q,
                                             const float* __restrict__ b_q,
                                             float* __restrict__ qf,
                                             const float* __restrict__ kvp,
                                             const float* __restrict__ b_ko,
                                             const float* __restrict__ buf,
                                             const float* __restrict__ inpT,
                                             float* __restrict__ xT2, int tv) {
  __shared__ float wl[8 * 1024];  // 32 KB
  __shared__ float pw[TT];
  int tid = threadIdx.x, lane = tid & 63, wid = tid >> 6;

  if (blockIdx.x >= 128) {
    // ---- history-attn finish for batch b ----
    int b = blockIdx.x - 128;
    if (tid < tv) {
      float s = b_ko[0];
#pragma unroll 8
      for (int g = 0; g < 64; ++g) s += kvp[((size_t)g * TT + tid) * 64 + b];  // ordered
      pw[tid] = s;
    }
    __syncthreads();
    float mx = -1e30f;
    for (int k = 0; k < tv; ++k) mx = fmaxf(mx, pw[k]);
    float den = 0.f;
    for (int k = 0; k < tv; ++k) den += expf(pw[k] - mx);
    float invd = 1.f / den;
    __syncthreads();
    if (tid < tv) pw[tid] = expf(pw[tid] - mx) * invd;
    __syncthreads();
    for (int e = tid; e < 512; e += 256) {
      float a = 0.f;
      for (int k = 0; k < tv; ++k) a += pw[k] * buf[((size_t)b * TT + k) * 512 + e];
      xT2[(1024 + e) * 64 + b] = inpT[e * 64 + b] + a;
    }
    return;
  }

  // ---- q GEMM half: 8 h-rows, intra-block split-K, LDS reduce -> qf[b][h] ----
  int h0 = blockIdx.x * 8;
  for (int i = tid; i < 2048; i += 256) {
    int lr = i >> 8, kq = i & 255;
    *(float4*)&wl[lr * 1024 + kq * 4] = *(const float4*)&w_q[(size_t)(h0 + lr) * 1024 + kq * 4];
  }
  __syncthreads();
  int kbase = wid * 256;
  const float* xp = h + (size_t)kbase * 64 + lane;
  float acc[8] = {0, 0, 0, 0, 0, 0, 0, 0};
#pragma unroll 2
  for (int k4 = 0; k4 < 64; ++k4) {
    float x0 = xp[(4 * k4 + 0) * 64];
    float x1 = xp[(4 * k4 + 1) * 64];
    float x2 = xp[(4 * k4 + 2) * 64];
    float x3 = xp[(4 * k4 + 3) * 64];
#pragma unroll
    for (int lr = 0; lr < 8; ++lr) {
      const float4 w4 = *(const float4*)&wl[lr * 1024 + kbase + 4 * k4];
      acc[lr] = fmaf(w4.x, x0, acc[lr]);
      acc[lr] = fmaf(w4.y, x1, acc[lr]);
      acc[lr] = fmaf(w4.z, x2, acc[lr]);
      acc[lr] = fmaf(w4.w, x3, acc[lr]);
    }
  }
  __syncthreads();
#pragma unroll
  for (int lr = 0; lr < 8; ++lr) wl[wid * 512 + lr * 64 + lane] = acc[lr];
  __syncthreads();
  for (int e = tid; e < 512; e += 256) {
    int lr = e >> 6, b = e & 63;
    float v = b_q[h0 + lr];
#pragma unroll
    for (int w = 0; w < 4; ++w) v += wl[w * 512 + lr * 64 + b];
    qf[(size_t)b * 1024 + h0 + lr] = v;
  }
}

// ---------------- flash attention: 16 s-splits, 8 rows/wave, pair-pipelined (R4-proven) ----------------
__global__ __launch_bounds__(256) void k_flash(const float* __restrict__ enc,
                                               const int* __restrict__ tlen,
                                               const float* __restrict__ qf,
                                               float* __restrict__ fm, float* __restrict__ fl,
                                               float* __restrict__ facc) {
  __shared__ float lacc[4][1024];
  __shared__ float lml[4][2];
  int b = blockIdx.x >> 4, split = blockIdx.x & 15;
  int tid = threadIdx.x, lane = tid & 63, wid = tid >> 6;
  int len = tlen[b];
  float qv[16];
#pragma unroll
  for (int j = 0; j < 4; ++j) {
    float4 tq = *(const float4*)&qf[(size_t)b * 1024 + j * 256 + lane * 4];
    qv[4 * j + 0] = tq.x; qv[4 * j + 1] = tq.y; qv[4 * j + 2] = tq.z; qv[4 * j + 3] = tq.w;
  }
  const float* base = enc + (size_t)b * SE * HD;
  int s0 = split * 32 + wid * 8;
  int nr = len - s0;
  nr = nr < 0 ? 0 : (nr > 8 ? 8 : nr);
  int npair = nr >> 1;

  float4 cA[4], cB[4], nA[4], nB[4];
  float m = -1e30f, l = 0.f, acc[16];
#pragma unroll
  for (int j = 0; j < 16; ++j) acc[j] = 0.f;

#define LOADROW(d, s)                                                 \
  {                                                                   \
    const float4* rp = (const float4*)(base + (size_t)(s)*HD) + lane; \
    d[0] = rp[0]; d[1] = rp[64]; d[2] = rp[128]; d[3] = rp[192];      \
  }

  if (npair > 0) { LOADROW(cA, s0); LOADROW(cB, s0 + 1); }
  for (int p = 0; p < npair; ++p) {
    if (p + 1 < npair) {
      LOADROW(nA, s0 + 2 * p + 2);
      LOADROW(nB, s0 + 2 * p + 3);
    } else if (nr & 1) {
      LOADROW(nA, s0 + nr - 1);
    }
    float d0 = 0.f, d1 = 0.f;
#pragma unroll
    for (int j = 0; j < 4; ++j) {
      d0 = fmaf(qv[4 * j + 0], cA[j].x, d0); d1 = fmaf(qv[4 * j + 0], cB[j].x, d1);
      d0 = fmaf(qv[4 * j + 1], cA[j].y, d0); d1 = fmaf(qv[4 * j + 1], cB[j].y, d1);
      d0 = fmaf(qv[4 * j + 2], cA[j].z, d0); d1 = fmaf(qv[4 * j + 2], cB[j].z, d1);
      d0 = fmaf(qv[4 * j + 3], cA[j].w, d0); d1 = fmaf(qv[4 * j + 3], cB[j].w, d1);
    }
#pragma unroll
    for (int off = 32; off; off >>= 1) { d0 += __shfl_xor(d0, off, 64); d1 += __shfl_xor(d1, off, 64); }
    d0 = __shfl(d0, 0, 64);
    d1 = __shfl(d1, 0, 64);
    float mn = fmaxf(m, fmaxf(d0, d1));
    float sc = expf(m - mn), p0 = expf(d0 - mn), p1 = expf(d1 - mn);
    l = l * sc + p0 + p1;
#pragma unroll
    for (int j = 0; j < 4; ++j) {
      acc[4 * j + 0] = fmaf(p1, cB[j].x, fmaf(p0, cA[j].x, acc[4 * j + 0] * sc));
      acc[4 * j + 1] = fmaf(p1, cB[j].y, fmaf(p0, cA[j].y, acc[4 * j + 1] * sc));
      acc[4 * j + 2] = fmaf(p1, cB[j].z, fmaf(p0, cA[j].z, acc[4 * j + 2] * sc));
      acc[4 * j + 3] = fmaf(p1, cB[j].w, fmaf(p0, cA[j].w, acc[4 * j + 3] * sc));
    }
    m = mn;
#pragma unroll
    for (int j = 0; j < 4; ++j) { cA[j] = nA[j]; cB[j] = nB[j]; }
  }
  if (nr & 1) {
    if (npair == 0) LOADROW(cA, s0);
    float d0 = 0.f;
#pragma unroll
    for (int j = 0; j < 4; ++j) {
      d0 = fmaf(qv[4 * j + 0], cA[j].x, d0);
      d0 = fmaf(qv[4 * j + 1], cA[j].y, d0);
      d0 = fmaf(qv[4 * j + 2], cA[j].z, d0);
      d0 = fmaf(qv[4 * j + 3], cA[j].w, d0);
    }
#pragma unroll
    for (int off = 32; off; off >>= 1) d0 += __shfl_xor(d0, off, 64);
    d0 = __shfl(d0, 0, 64);
    float mn = fmaxf(m, d0);
    float sc = expf(m - mn), p0 = expf(d0 - mn);
    l = l * sc + p0;
#pragma unroll
    for (int j = 0; j < 4; ++j) {
      acc[4 * j + 0] = fmaf(p0, cA[j].x, acc[4 * j + 0] * sc);
      acc[4 * j + 1] = fmaf(p0, cA[j].y, acc[4 * j + 1] * sc);
      acc[4 * j + 2] = fmaf(p0, cA[j].z, acc[4 * j + 2] * sc);
      acc[4 * j + 3] = fmaf(p0, cA[j].w, acc[4 * j + 3] * sc);
    }
    m = mn;
  }
#undef LOADROW
#pragma unroll
  for (int j = 0; j < 4; ++j)
    *(float4*)&lacc[wid][j * 256 + lane * 4] =
        make_float4(acc[4 * j], acc[4 * j + 1], acc[4 * j + 2], acc[4 * j + 3]);
  if (lane == 0) { lml[wid][0] = m; lml[wid][1] = l; }
  __syncthreads();
  float M = fmaxf(fmaxf(lml[0][0], lml[1][0]), fmaxf(lml[2][0], lml[3][0]));
  float w0 = expf(lml[0][0] - M), w1 = expf(lml[1][0] - M);
  float w2 = expf(lml[2][0] - M), w3 = expf(lml[3][0] - M);
  float L = w0 * lml[0][1] + w1 * lml[1][1] + w2 * lml[2][1] + w3 * lml[3][1];
  int p = b * 16 + split;
  for (int h = tid; h < 1024; h += 256)
    facc[(size_t)p * 1024 + h] =
        w0 * lacc[0][h] + w1 * lacc[1][h] + w2 * lacc[2][h] + w3 * lacc[3][h];
  if (tid == 0) { fm[p] = M; fl[p] = L; }
}

// ---------------- flash combine only -> xT2[0:1024) (256 blocks: b x quarter) ----------------
__global__ __launch_bounds__(256) void k_ctx(const float* __restrict__ enc,
                                             const float* __restrict__ fm,
                                             const float* __restrict__ fl,
                                             const float* __restrict__ facc,
                                             float* __restrict__ xT2) {
  int b = blockIdx.x >> 2, qd = blockIdx.x & 3;
  int tid = threadIdx.x;
  float M = -1e30f;
#pragma unroll
  for (int k = 0; k < 16; ++k) M = fmaxf(M, fm[b * 16 + k]);
  float w[16];
  float L = 0.f;
#pragma unroll
  for (int k = 0; k < 16; ++k) {
    w[k] = expf(fm[b * 16 + k] - M);
    L += w[k] * fl[b * 16 + k];
  }
  float inv = 1.f / L;
  int h = qd * 256 + tid;
  float s = 0.f;
#pragma unroll
  for (int k = 0; k < 16; ++k) s += w[k] * facc[(size_t)(b * 16 + k) * 1024 + h];
  xT2[h * 64 + b] = enc[(size_t)b * SE * HD + h] + s * inv;  // sent = enc[:,0,:]
}

// ---------------- fused h1 GEMM: intra-block split-K + bias+relu -> h1T ----------------
__global__ __launch_bounds__(256) void k_h12(const float* __restrict__ xT2,
                                             const float* __restrict__ w_m1,
                                             const float* __restrict__ b_m1,
                                             float* __restrict__ h1T) {
  __shared__ float wl[8 * 1536];  // 48 KB
  int tid = threadIdx.x;
  int r0 = blockIdx.x * 8;
  for (int i = tid; i < 3072; i += 256) {
    int lr = i / 384, kq = i % 384;
    *(float4*)&wl[lr * 1536 + kq * 4] = *(const float4*)&w_m1[(size_t)(r0 + lr) * MM + kq * 4];
  }
  __syncthreads();
  int lane = tid & 63, wid = tid >> 6;
  int kbase = wid * 384;
  const float* xp = xT2 + (size_t)kbase * 64 + lane;
  float acc[8] = {0, 0, 0, 0, 0, 0, 0, 0};
#pragma unroll 2
  for (int k4 = 0; k4 < 96; ++k4) {
    float x0 = xp[(4 * k4 + 0) * 64];
    float x1 = xp[(4 * k4 + 1) * 64];
    float x2 = xp[(4 * k4 + 2) * 64];
    float x3 = xp[(4 * k4 + 3) * 64];
#pragma unroll
    for (int lr = 0; lr < 8; ++lr) {
      const float4 w4 = *(const float4*)&wl[lr * 1536 + kbase + 4 * k4];
      acc[lr] = fmaf(w4.x, x0, acc[lr]);
      acc[lr] = fmaf(w4.y, x1, acc[lr]);
      acc[lr] = fmaf(w4.z, x2, acc[lr]);
      acc[lr] = fmaf(w4.w, x3, acc[lr]);
    }
  }
  __syncthreads();
#pragma unroll
  for (int lr = 0; lr < 8; ++lr) wl[wid * 512 + lr * 64 + lane] = acc[lr];
  __syncthreads();
  for (int e = tid; e < 512; e += 256) {
    int lr = e >> 6, b = e & 63;
    float v = b_m1[r0 + lr];
#pragma unroll
    for (int w = 0; w < 4; ++w) v += wl[w * 512 + lr * 64 + b];
    h1T[(size_t)(r0 + lr) * 64 + b] = fmaxf(v, 0.f);
  }
}

// ---------------- vocab GEMM: BM=128, split 6, 8x4 thread tiles (R9-proven geometry) ----------------
__global__ __launch_bounds__(256) void k_vocab(const float* __restrict__ h1T,
                                               const float* __restrict__ w_m2,
                                               float* __restrict__ lp) {
  __shared__ float Wl[128 * 36];  // [row][36] (BK=32 + pad 4) -> 18 KB
  __shared__ float Xl[32 * 68];   // [k][68]  (64 + pad 4)     -> 8.5 KB
  int tid = threadIdx.x;
  int r0b = blockIdx.x * 128;  // 0..78
  int k0 = blockIdx.y * 256;   // 0..5
  int tc = tid & 15, tr = tid >> 4;
  int r0 = tr * 8, b0 = tc * 4;
  float4 acc[8];
#pragma unroll
  for (int i = 0; i < 8; ++i) acc[i] = make_float4(0.f, 0.f, 0.f, 0.f);
  for (int kt = 0; kt < 8; ++kt) {
    int kbase = k0 + kt * 32;
    // stage W tile: 128 rows x 32 k (1024 float4)
#pragma unroll
    for (int j = 0; j < 4; ++j) {
      int f = tid + 256 * j;
      int row = f >> 3, kkq = (f & 7) * 4;
      int gr = r0b + row;
      if (gr > NV - 1) gr = NV - 1;
      *(float4*)&Wl[row * 36 + kkq] = *(const float4*)&w_m2[(size_t)gr * MM + kbase + kkq];
    }
    // stage X tile: 32 k x 64 b (512 float4)
#pragma unroll
    for (int j = 0; j < 2; ++j) {
      int f = tid + 256 * j;
      int kk = f >> 4, bq = (f & 15) * 4;
      *(float4*)&Xl[kk * 68 + bq] = *(const float4*)&h1T[(size_t)(kbase + kk) * 64 + bq];
    }
    __syncthreads();
#pragma unroll 2
    for (int kq = 0; kq < 8; ++kq) {
      float4 xv0 = *(const float4*)&Xl[(kq * 4 + 0) * 68 + b0];
      float4 xv1 = *(const float4*)&Xl[(kq * 4 + 1) * 68 + b0];
      float4 xv2 = *(const float4*)&Xl[(kq * 4 + 2) * 68 + b0];
      float4 xv3 = *(const float4*)&Xl[(kq * 4 + 3) * 68 + b0];
#pragma unroll
      for (int i = 0; i < 8; ++i) {
        float4 av = *(const float4*)&Wl[(r0 + i) * 36 + kq * 4];
        acc[i].x = fmaf(av.x, xv0.x, acc[i].x);
        acc[i].y = fmaf(av.x, xv0.y, acc[i].y);
        acc[i].z = fmaf(av.x, xv0.z, acc[i].z);
        acc[i].w = fmaf(av.x, xv0.w, acc[i].w);
        acc[i].x = fmaf(av.y, xv1.x, acc[i].x);
        acc[i].y = fmaf(av.y, xv1.y, acc[i].y);
        acc[i].z = fmaf(av.y, xv1.z, acc[i].z);
        acc[i].w = fmaf(av.y, xv1.w, acc[i].w);
        acc[i].x = fmaf(av.z, xv2.x, acc[i].x);
        acc[i].y = fmaf(av.z, xv2.y, acc[i].y);
        acc[i].z = fmaf(av.z, xv2.z, acc[i].z);
        acc[i].w = fmaf(av.z, xv2.w, acc[i].w);
        acc[i].x = fmaf(av.w, xv3.x, acc[i].x);
        acc[i].y = fmaf(av.w, xv3.y, acc[i].y);
        acc[i].z = fmaf(av.w, xv3.z, acc[i].z);
        acc[i].w = fmaf(av.w, xv3.w, acc[i].w);
      }
    }
    __syncthreads();
  }
  float* o = lp + (size_t)blockIdx.y * 640000;
#pragma unroll
  for (int i = 0; i < 8; ++i) {
    int r = r0b + r0 + i;
    if (r < NV) *(float4*)&o[(size_t)r * 64 + b0] = acc[i];
  }
}

// ---------------- logits finish: combine 6 + bias + mask + argmax partial + transposed out ----------------
__global__ __launch_bounds__(256) void k_logfin(const float* __restrict__ lp,
                                                const float* __restrict__ b_m2,
                                                const float* __restrict__ maskT,
                                                float* __restrict__ argv, int* __restrict__ argi,
                                                float* __restrict__ out, int t) {
  __shared__ float tile[32][65];
  int lane = threadIdx.x & 63, wid = threadIdx.x >> 6;
  int rg = blockIdx.x * 4 + wid;
  int nb = blockIdx.x * 32;
  if (rg < 1250) {
    int r0 = rg * 8;
    float best = -3.4e38f;
    int bi = 0;
#pragma unroll
    for (int i = 0; i < 8; ++i) {
      int r = r0 + i;
      size_t idx = (size_t)r * 64 + lane;
      float v = b_m2[r] + maskT[idx];
#pragma unroll
      for (int s = 0; s < 6; ++s) v += lp[(size_t)s * 640000 + idx];
      tile[wid * 8 + i][lane] = v;
      if (v > best) { best = v; bi = r; }  // strict >: first-max (np.argmax)
    }
    argv[(size_t)rg * 64 + lane] = best;
    argi[(size_t)rg * 64 + lane] = bi;
  }
  __syncthreads();
  int b = threadIdx.x >> 2, q = threadIdx.x & 3;
  int nloc = q * 8;
  if (nb + nloc < NV) {
    float tmp[8];
#pragma unroll
    for (int c = 0; c < 8; ++c) tmp[c] = tile[nloc + c][b];
    float4* o = (float4*)&out[((size_t)b * TT + t) * NV + nb + nloc];
    o[0] = make_float4(tmp[0], tmp[1], tmp[2], tmp[3]);
    o[1] = make_float4(tmp[4], tmp[5], tmp[6], tmp[7]);
  }
}

// ---------------- final argmax (per-batch block) + feedback ----------------
__global__ __launch_bounds__(256) void k_final(const float* __restrict__ argv,
                                               const int* __restrict__ argi,
                                               const float* __restrict__ emb,
                                               float* __restrict__ maskT,
                                               float* __restrict__ xnext,  // inp section dest
                                               float* __restrict__ buf, float* __restrict__ bufT,
                                               float* __restrict__ out_ids, int t) {
  __shared__ float sv[256];
  __shared__ int si_[256];
  __shared__ int sid;
  int b = blockIdx.x, tid = threadIdx.x;
  float best = -3.4e38f;
  int bi = 0x7fffffff;
  for (int g = tid; g < 1250; g += 256) {
    float v = argv[(size_t)g * 64 + b];
    int idx = argi[(size_t)g * 64 + b];
    if (v > best || (v == best && idx < bi)) { best = v; bi = idx; }
  }
  sv[tid] = best;
  si_[tid] = bi;
  __syncthreads();
  for (int off = 128; off; off >>= 1) {
    if (tid < off) {
      float v2 = sv[tid + off];
      int i2 = si_[tid + off];
      if (v2 > sv[tid] || (v2 == sv[tid] && i2 < si_[tid])) { sv[tid] = v2; si_[tid] = i2; }
    }
    __syncthreads();
  }
  if (tid == 0) {
    sid = si_[0];
    out_ids[b * TT + t] = (float)si_[0];
    if (si_[0] != 1) maskT[(size_t)si_[0] * 64 + b] = MASK_VALF;  // EOS(1) stays 0
  }
  __syncthreads();
  int id = sid;
  for (int e = tid; e < 512; e += 256) {
    float v = emb[(size_t)id * 512 + e];
    xnext[e * 64 + b] = v;  // inp for next step
    buf[((size_t)b * TT + t) * 512 + e] = v;
    bufT[(size_t)e * (TT * 64) + t * 64 + b] = v;
  }
}

extern "C" void kernel_launch(void* const* d_in, const int* in_sizes, int n_in,
                              void* d_out, int out_size, void* d_ws, size_t ws_size,
                              hipStream_t stream) {
  const float* enc = (const float*)d_in[0];
  const float* h0 = (const float*)d_in[1];
  const float* c0 = (const float*)d_in[2];
  const int* tlen = (const int*)d_in[3];
  const float* emb = (const float*)d_in[5];
  const float* w_ih = (const float*)d_in[6];
  const float* w_hh = (const float*)d_in[7];
  const float* b_ih = (const float*)d_in[8];
  const float* b_hh = (const float*)d_in[9];
  const float* w_q = (const float*)d_in[10];
  const float* b_q = (const float*)d_in[11];
  const float* w_k = (const float*)d_in[12];
  const float* b_k = (const float*)d_in[13];
  const float* w_ko = (const float*)d_in[14];
  const float* b_ko = (const float*)d_in[15];
  const float* w_m1 = (const float*)d_in[16];
  const float* b_m1 = (const float*)d_in[17];
  const float* w_m2 = (const float*)d_in[18];
  const float* b_m2 = (const float*)d_in[19];

  float* ws = (float*)d_ws;
  float* out_logits = (float*)d_out;
  float* out_ids = out_logits + (size_t)B64 * TT * NV;

  k_init<<<2048, 256, 0, stream>>>(h0, c0, ws);

  for (int t = 0; t < TT; ++t) {
    int tv = (t < 1) ? 1 : t;
    int jcol = (t == 0) ? 0 : t - 1;  // kscore column: zeros at t=0, else buf col written at t-1
    float* xcur = ws + ((t & 1) ? OFF_XB : OFF_XA);
    float* xnext = ws + ((t & 1) ? OFF_XA : OFF_XB);
    k_cellks<<<576, 256, 0, stream>>>(xcur, w_ih, w_hh, b_ih, b_hh, ws + OFF_CT, xnext,
                                      ws + OFF_BUFT, w_k, b_k, w_ko, ws + OFF_KVP, jcol);
    k_q2h<<<192, 256, 0, stream>>>(xnext + 512 * 64, w_q, b_q, ws + OFF_QF, ws + OFF_KVP, b_ko,
                                   ws + OFF_BUF, xcur, ws + OFF_XT2, tv);
    k_flash<<<1024, 256, 0, stream>>>(enc, tlen, ws + OFF_QF, ws + OFF_FM, ws + OFF_FL,
                                      ws + OFF_FACC);
    k_ctx<<<256, 256, 0, stream>>>(enc, ws + OFF_FM, ws + OFF_FL, ws + OFF_FACC, ws + OFF_XT2);
    k_h12<<<192, 256, 0, stream>>>(ws + OFF_XT2, w_m1, b_m1, ws + OFF_H1T);
    k_vocab<<<dim3(79, 6), 256, 0, stream>>>(ws + OFF_H1T, w_m2, ws + OFF_LP);
    k_logfin<<<313, 256, 0, stream>>>(ws + OFF_LP, b_m2, ws + OFF_MASKT, ws + OFF_ARGV,
                                      (int*)(ws + OFF_ARGI), out_logits, t);
    k_final<<<64, 256, 0, stream>>>(ws + OFF_ARGV, (int*)(ws + OFF_ARGI), emb, ws + OFF_MASKT,
                                    xnext, ws + OFF_BUF, ws + OFF_BUFT, out_ids, t);
  }
}